// Round 10
// baseline (68.996 us; speedup 1.0000x reference)
//
#include <hip/hip_runtime.h>

#define N_SEQ 2048
#define NH 16
#define DH 64
#define CHUNK 64
#define NCHUNK 32

typedef float f32x4 __attribute__((ext_vector_type(4)));
typedef float f32x16 __attribute__((ext_vector_type(16)));
typedef __bf16 bf16x8 __attribute__((ext_vector_type(8)));
typedef unsigned short u16x4 __attribute__((ext_vector_type(4)));
typedef unsigned short u16x8 __attribute__((ext_vector_type(8)));

static __device__ inline unsigned short f2b(float x) {
    unsigned int u = __builtin_bit_cast(unsigned int, x);
    unsigned int r = (u + 0x7fffu + ((u >> 16) & 1u)) >> 16;  // RNE
    return (unsigned short)r;
}
static __device__ inline float b2f(unsigned short b) {
    return __builtin_bit_cast(float, (unsigned int)b << 16);
}
// swizzled elem offset in a [rows][64 bf16] LDS tile (row stride 128B)
static __device__ inline int sw(int row, int col) {
    return row * 64 + (col ^ ((row & 7) << 3));
}

// ---------------------------------------------------------------- fused casts (X + 4 weights) + zero norm buffer
__global__ __launch_bounds__(256) void cast_all(
    const float* __restrict__ X, const float* __restrict__ Wq, const float* __restrict__ Wk,
    const float* __restrict__ Wv, const float* __restrict__ Wo,
    unsigned short* __restrict__ Xb, unsigned short* __restrict__ Wb,
    unsigned short* __restrict__ Wob, float* __restrict__ nrm) {
    if (blockIdx.x == 0 && threadIdx.x < 32) nrm[threadIdx.x] = 0.f;
    int i = blockIdx.x * 256 + threadIdx.x;     // float4 id, total 1572864
    const float* src; unsigned short* dst; int off;
    if (i < 524288)       { src = X;  dst = Xb;               off = i; }
    else if (i < 786432)  { src = Wq; dst = Wb;               off = i - 524288; }
    else if (i < 1048576) { src = Wk; dst = Wb + (1u << 20);  off = i - 786432; }
    else if (i < 1310720) { src = Wv; dst = Wb + (2u << 20);  off = i - 1048576; }
    else                  { src = Wo; dst = Wob;              off = i - 1310720; }
    float4 v = reinterpret_cast<const float4*>(src)[off];
    u16x4 o;
    o[0] = f2b(v.x); o[1] = f2b(v.y); o[2] = f2b(v.z); o[3] = f2b(v.w);
    reinterpret_cast<u16x4*>(dst)[off] = o;
}

// ---------------------------------------------------------------- async global -> LDS (16B/lane)
static __device__ inline void gload_lds16(const unsigned short* g, unsigned short* l) {
    __builtin_amdgcn_global_load_lds(
        (const __attribute__((address_space(1))) unsigned int*)g,
        (__attribute__((address_space(3))) unsigned int*)l, 16, 0, 0);
}

// ---------------------------------------------------------------- QKV GEMM: 32x32x16 MFMA, 128x64 tile, BK=64
// writes bf16 QKV [which][h][n][d]; block owns ONE (which, head) -> fused per-head max row-sumsq
__global__ __launch_bounds__(256, 2) void gemm_qkv(
    const unsigned short* __restrict__ A,
    const unsigned short* __restrict__ B,
    unsigned short* __restrict__ outb,
    float* __restrict__ nrm,
    int K)
{
    __shared__ __align__(16) unsigned short As[128][64];
    __shared__ __align__(16) unsigned short Bs[64][64];
    __shared__ float pnorm[2][128];

    // XCD-aware bijective swizzle (768 blocks % 8 == 0), bn-major chunks
    const int L = blockIdx.y * gridDim.x + blockIdx.x;
    const int cpx = (gridDim.x * gridDim.y) >> 3;
    const int tile = (L & 7) * cpx + (L >> 3);
    const int bn = tile / gridDim.y;     // 0..47 (one (which, head) per bn)
    const int bm = tile % gridDim.y;     // 0..15

    const int t = threadIdx.x;
    const int wave = t >> 6, lane = t & 63;
    const int wm = wave >> 1, wn = wave & 1;
    const int l31 = lane & 31, lhi = lane >> 5;

    f32x16 acc0 = {};    // rows wm*64 + 0..31
    f32x16 acc1 = {};    // rows wm*64 + 32..63

    const unsigned short* gA = A + (size_t)bm * 128 * K;
    const unsigned short* gB = B + (size_t)bn * 64 * K;
    const int lrow = lane >> 3;                              // 0..7
    const int scol = (((lane & 7) ^ (lrow & 7)) << 3);       // pre-swizzled source col (elems)

    for (int k0 = 0; k0 < K; k0 += 64) {
        __syncthreads();
        #pragma unroll
        for (int g2 = 0; g2 < 4; ++g2) {
            int r0 = wave * 32 + g2 * 8;
            gload_lds16(&gA[(size_t)(r0 + lrow) * K + k0 + scol], &As[r0][0]);
        }
        #pragma unroll
        for (int g2 = 0; g2 < 2; ++g2) {
            int r0 = wave * 16 + g2 * 8;
            gload_lds16(&gB[(size_t)(r0 + lrow) * K + k0 + scol], &Bs[r0][0]);
        }
        __syncthreads();

        #pragma unroll
        for (int ks2 = 0; ks2 < 4; ++ks2) {
            // logical elem col = ks2*16 + 8*lhi ; row&7 == lane&7 for all operand rows
            const int cb = (ks2 * 16 + (lhi << 3)) ^ ((lane & 7) << 3);
            bf16x8 a0 = *reinterpret_cast<const bf16x8*>(&As[wm * 64 + l31][cb]);
            bf16x8 a1 = *reinterpret_cast<const bf16x8*>(&As[wm * 64 + 32 + l31][cb]);
            bf16x8 bb = *reinterpret_cast<const bf16x8*>(&Bs[wn * 32 + l31][cb]);
            acc0 = __builtin_amdgcn_mfma_f32_32x32x16_bf16(a0, bb, acc0, 0, 0, 0);
            acc1 = __builtin_amdgcn_mfma_f32_32x32x16_bf16(a1, bb, acc1, 0, 0, 0);
        }
    }

    // epilogue: C layout col=lane&31, row=(r&3)+8*(r>>2)+4*(lane>>5)
    const int wch = bn >> 4;             // 0 q, 1 k, 2 v
    const int h = bn & 15;
    const int d = wn * 32 + l31;
    unsigned short* dst = outb + (size_t)wch * (NH * (size_t)N_SEQ * DH)
                               + (size_t)h * N_SEQ * DH + d;
    #pragma unroll
    for (int r = 0; r < 16; ++r) {
        int crow = (r & 3) + 8 * (r >> 2) + 4 * lhi;
        int row0 = bm * 128 + wm * 64 + crow;
        dst[(size_t)row0 * DH] = f2b(acc0[r]);
        dst[(size_t)(row0 + 32) * DH] = f2b(acc1[r]);
    }

    // fused per-head max row-sumsq (q,k only)
    if (wch < 2) {
        #pragma unroll
        for (int r = 0; r < 16; ++r) {
            int crow = (r & 3) + 8 * (r >> 2) + 4 * lhi;
            float r0 = acc0[r] * acc0[r];
            float r1 = acc1[r] * acc1[r];
            #pragma unroll
            for (int o = 1; o < 32; o <<= 1) {
                r0 += __shfl_xor(r0, o);
                r1 += __shfl_xor(r1, o);
            }
            if (l31 == 0) {
                pnorm[wn][wm * 64 + crow] = r0;
                pnorm[wn][wm * 64 + 32 + crow] = r1;
            }
        }
        __syncthreads();
        if (t < 128) {
            float s = pnorm[0][t] + pnorm[1][t];
            #pragma unroll
            for (int o = 1; o < 64; o <<= 1) s = fmaxf(s, __shfl_xor(s, o));
            if ((t & 63) == 0)
                atomicMax(reinterpret_cast<unsigned int*>(&nrm[wch * 16 + h]),
                          __builtin_bit_cast(unsigned int, s));
        }
    }
}

// ---------------------------------------------------------------- out-proj GEMM (16x16x32, 64x128 tile, BK=64)
__global__ __launch_bounds__(256, 2) void gemm_out(
    const unsigned short* __restrict__ A,
    const unsigned short* __restrict__ B,
    float* __restrict__ outf,
    const float* __restrict__ bias,
    int N, int K)
{
    __shared__ __align__(16) unsigned short As[64][64];
    __shared__ __align__(16) unsigned short Bs[128][64];

    const int L = blockIdx.y * gridDim.x + blockIdx.x;
    const int cpx = (gridDim.x * gridDim.y) >> 3;
    const int tile = (L & 7) * cpx + (L >> 3);
    const int bn = tile / gridDim.y;
    const int bm = tile % gridDim.y;

    const int t = threadIdx.x;
    const int wave = t >> 6, lane = t & 63;
    const int wm = wave >> 1, wn = wave & 1;
    const int r16 = lane & 15, ks = lane >> 4;

    f32x4 acc[2][4] = {};

    const unsigned short* gA = A + (size_t)bm * 64 * K;
    const unsigned short* gB = B + (size_t)bn * 128 * K;
    const int lrow = lane >> 3;
    const int scol = (((lane & 7) ^ (lrow & 7)) << 3);
    const int rsw = (r16 & 7) << 3;

    for (int k0 = 0; k0 < K; k0 += 64) {
        __syncthreads();
        #pragma unroll
        for (int g2 = 0; g2 < 2; ++g2) {
            int r0 = wave * 16 + g2 * 8;
            gload_lds16(&gA[(size_t)(r0 + lrow) * K + k0 + scol], &As[r0][0]);
        }
        #pragma unroll
        for (int g2 = 0; g2 < 4; ++g2) {
            int r0 = wave * 32 + g2 * 8;
            gload_lds16(&gB[(size_t)(r0 + lrow) * K + k0 + scol], &Bs[r0][0]);
        }
        __syncthreads();

        #pragma unroll
        for (int ksub = 0; ksub < 2; ++ksub) {
            const int sl = (((ksub << 2) + ks) << 3) ^ rsw;
            bf16x8 af[2], bfr[4];
            #pragma unroll
            for (int m = 0; m < 2; ++m)
                af[m] = *reinterpret_cast<const bf16x8*>(&As[wm * 32 + m * 16 + r16][sl]);
            #pragma unroll
            for (int n = 0; n < 4; ++n)
                bfr[n] = *reinterpret_cast<const bf16x8*>(&Bs[wn * 64 + n * 16 + r16][sl]);
            #pragma unroll
            for (int m = 0; m < 2; ++m)
                #pragma unroll
                for (int n = 0; n < 4; ++n)
                    acc[m][n] = __builtin_amdgcn_mfma_f32_16x16x32_bf16(af[m], bfr[n], acc[m][n], 0, 0, 0);
        }
    }

    #pragma unroll
    for (int m = 0; m < 2; ++m) {
        int row0 = bm * 64 + wm * 32 + m * 16 + ks * 4;
        #pragma unroll
        for (int n = 0; n < 4; ++n) {
            int col = bn * 128 + wn * 64 + n * 16 + r16;
            float bv = bias[col];
            #pragma unroll
            for (int j = 0; j < 4; ++j)
                outf[(size_t)(row0 + j) * N + col] = acc[m][n][j] + bv;
        }
    }
}

// ---------------------------------------------------------------- per-chunk sums via MFMA: S = K^T V (bf16 out), z, vs
__global__ __launch_bounds__(256) void chunk_sums(const unsigned short* __restrict__ Kb,
                                                  const unsigned short* __restrict__ Vb,
                                                  unsigned short* __restrict__ Ssum,
                                                  float* __restrict__ zsum,
                                                  float* __restrict__ vssum) {
    const int h = blockIdx.x >> 5, c = blockIdx.x & 31;
    __shared__ __align__(16) unsigned short Kt[4096];   // [d][j] swizzled (= K^T)
    __shared__ __align__(16) unsigned short Vt[4096];   // [e][j] swizzled (= V^T)
    const size_t off = ((size_t)h * N_SEQ + c * CHUNK) * DH;
    const int t = threadIdx.x, lane = t & 63;

    {   // transposed gather
        const int d = t & 63, j0 = (t >> 6) * 16;
        unsigned short rk[16], rv[16];
        #pragma unroll
        for (int i = 0; i < 16; ++i) {
            rk[i] = Kb[off + (size_t)(j0 + i) * DH + d];
            rv[i] = Vb[off + (size_t)(j0 + i) * DH + d];
        }
        u16x8 a, b;
        #pragma unroll
        for (int i = 0; i < 8; ++i) { a[i] = rk[i]; b[i] = rk[8 + i]; }
        *reinterpret_cast<u16x8*>(&Kt[sw(d, j0)]) = a;
        *reinterpret_cast<u16x8*>(&Kt[sw(d, j0 + 8)]) = b;
        #pragma unroll
        for (int i = 0; i < 8; ++i) { a[i] = rv[i]; b[i] = rv[8 + i]; }
        *reinterpret_cast<u16x8*>(&Vt[sw(d, j0)]) = a;
        *reinterpret_cast<u16x8*>(&Vt[sw(d, j0 + 8)]) = b;
    }
    __syncthreads();

    const int w = t >> 6, cl = lane & 15, g = lane >> 4;
    bf16x8 ak0 = *reinterpret_cast<const bf16x8*>(&Kt[sw(w * 16 + cl, g * 8)]);
    bf16x8 ak1 = *reinterpret_cast<const bf16x8*>(&Kt[sw(w * 16 + cl, 32 + g * 8)]);
    f32x4 acc[4] = {};
    #pragma unroll
    for (int et = 0; et < 4; ++et) {
        bf16x8 b0 = *reinterpret_cast<const bf16x8*>(&Vt[sw(et * 16 + cl, g * 8)]);
        bf16x8 b1 = *reinterpret_cast<const bf16x8*>(&Vt[sw(et * 16 + cl, 32 + g * 8)]);
        acc[et] = __builtin_amdgcn_mfma_f32_16x16x32_bf16(ak0, b0, acc[et], 0, 0, 0);
        acc[et] = __builtin_amdgcn_mfma_f32_16x16x32_bf16(ak1, b1, acc[et], 0, 0, 0);
    }
    unsigned short* So = Ssum + (size_t)blockIdx.x * (DH * DH);
    #pragma unroll
    for (int et = 0; et < 4; ++et)
        #pragma unroll
        for (int j = 0; j < 4; ++j)
            So[(size_t)(w * 16 + g * 4 + j) * DH + et * 16 + cl] = f2b(acc[et][j]);

    if (t < 64) {
        float z = 0.f;
        #pragma unroll
        for (int i = 0; i < 8; ++i) {
            u16x8 v = *reinterpret_cast<const u16x8*>(&Kt[sw(t, i * 8)]);
            #pragma unroll
            for (int k = 0; k < 8; ++k) z += b2f(v[k]);
        }
        zsum[(size_t)blockIdx.x * DH + t] = z;
    } else if (t < 128) {
        int e = t - 64;
        float z = 0.f;
        #pragma unroll
        for (int i = 0; i < 8; ++i) {
            u16x8 v = *reinterpret_cast<const u16x8*>(&Vt[sw(e, i * 8)]);
            #pragma unroll
            for (int k = 0; k < 8; ++k) z += b2f(v[k]);
        }
        vssum[(size_t)blockIdx.x * DH + e] = z;
    }
}

// ---------------------------------------------------------------- exclusive scan over chunks (f32 run, bf16 in-place)
__global__ __launch_bounds__(256) void chunk_scan(unsigned short* __restrict__ Ssum,
                                                  float* __restrict__ zsum,
                                                  float* __restrict__ vssum) {
    const int b = blockIdx.x;
    if (b < 256) {
        const int h = b >> 4;
        const int e = (b & 15) * 256 + threadIdx.x;
        size_t base = (size_t)h * NCHUNK * (DH * DH) + e;
        float run = 0.f;
        for (int c = 0; c < NCHUNK; ++c) {
            size_t idx = base + (size_t)c * (DH * DH);
            float tmp = b2f(Ssum[idx]); Ssum[idx] = f2b(run); run += tmp;
        }
    } else {
        const int g = (b - 256) * 256 + threadIdx.x;
        const int which = g >> 10, h = (g >> 6) & 15, e = g & 63;
        float* arr = which ? vssum : zsum;
        size_t base = (size_t)h * NCHUNK * DH + e;
        float run = 0.f;
        for (int c = 0; c < NCHUNK; ++c) {
            size_t idx = base + (size_t)c * DH;
            float tmp = arr[idx]; arr[idx] = run; run += tmp;
        }
    }
}

// ---------------------------------------------------------------- intra-chunk attention + combine, MFMA
__global__ __launch_bounds__(256) void intra_attn(
    const unsigned short* __restrict__ Qb, const unsigned short* __restrict__ Kb,
    const unsigned short* __restrict__ Vb,
    const unsigned short* __restrict__ Ssum, const float* __restrict__ zsum,
    const float* __restrict__ vssum, const float* __restrict__ nrm,
    unsigned short* __restrict__ vhb) {
    const int h = blockIdx.x >> 5, c = blockIdx.x & 31;
    __shared__ __align__(16) unsigned short Ql[4096];   // [q][d] swizzled
    __shared__ __align__(16) unsigned short Kl[4096];   // [key][d] swizzled
    __shared__ __align__(16) unsigned short Vt[4096];   // [e][key] swizzled
    __shared__ __align__(16) unsigned short Sp[4096];   // [e][d] = bf16(alpha*S_prev[d][e]) swizzled
    __shared__ __align__(16) unsigned short Pl[4096];   // per-wave [16][64] swizzled
    __shared__ float zp[DH], vsp[DH];

    const int t = threadIdx.x, lane = t & 63, w = t >> 6;
    const float alpha = 1.f / sqrtf(nrm[h] * nrm[16 + h]);   // 1/(qn*kn), nrm = max sumsq
    const size_t off = ((size_t)h * N_SEQ + c * CHUNK) * DH;

    // Q, K: row-major coalesced loads, swizzled 16B writes
    #pragma unroll
    for (int p = 0; p < 2; ++p) {
        int lin = t + p * 256;
        int row = lin >> 3, col = (lin & 7) * 8;
        u16x8 q = *reinterpret_cast<const u16x8*>(Qb + off + (size_t)row * DH + col);
        u16x8 k = *reinterpret_cast<const u16x8*>(Kb + off + (size_t)row * DH + col);
        *reinterpret_cast<u16x8*>(&Ql[sw(row, col)]) = q;
        *reinterpret_cast<u16x8*>(&Kl[sw(row, col)]) = k;
    }
    // V transposed gather
    {
        const int e = t & 63, j0 = (t >> 6) * 16;
        unsigned short rv[16];
        #pragma unroll
        for (int i = 0; i < 16; ++i) rv[i] = Vb[off + (size_t)(j0 + i) * DH + e];
        u16x8 a, b;
        #pragma unroll
        for (int i = 0; i < 8; ++i) { a[i] = rv[i]; b[i] = rv[8 + i]; }
        *reinterpret_cast<u16x8*>(&Vt[sw(e, j0)]) = a;
        *reinterpret_cast<u16x8*>(&Vt[sw(e, j0 + 8)]) = b;
    }
    // S_prev transposed gather (bf16 in), alpha-prescaled
    {
        const unsigned short* Sg = Ssum + (size_t)blockIdx.x * (DH * DH);
        const int e = t & 63, d0 = (t >> 6) * 16;
        u16x8 a, b;
        #pragma unroll
        for (int i = 0; i < 8; ++i) a[i] = f2b(alpha * b2f(Sg[(size_t)(d0 + i) * DH + e]));
        #pragma unroll
        for (int i = 0; i < 8; ++i) b[i] = f2b(alpha * b2f(Sg[(size_t)(d0 + 8 + i) * DH + e]));
        *reinterpret_cast<u16x8*>(&Sp[sw(e, d0)]) = a;
        *reinterpret_cast<u16x8*>(&Sp[sw(e, d0 + 8)]) = b;
    }
    if (t < 64) zp[t] = alpha * zsum[(size_t)blockIdx.x * DH + t];
    else if (t < 128) vsp[t - 64] = vssum[(size_t)blockIdx.x * DH + (t - 64)];
    __syncthreads();

    const int cl = lane & 15, g = lane >> 4;
    const int qrow = (w << 4) + cl;

    bf16x8 aq0 = *reinterpret_cast<const bf16x8*>(&Ql[sw(qrow, g * 8)]);
    bf16x8 aq1 = *reinterpret_cast<const bf16x8*>(&Ql[sw(qrow, 32 + g * 8)]);

    // 1) acc = Q @ (alpha*S_prev)
    f32x4 acc[4] = {};
    #pragma unroll
    for (int et = 0; et < 4; ++et) {
        bf16x8 b0 = *reinterpret_cast<const bf16x8*>(&Sp[sw(et * 16 + cl, g * 8)]);
        bf16x8 b1 = *reinterpret_cast<const bf16x8*>(&Sp[sw(et * 16 + cl, 32 + g * 8)]);
        acc[et] = __builtin_amdgcn_mfma_f32_16x16x32_bf16(aq0, b0, acc[et], 0, 0, 0);
        acc[et] = __builtin_amdgcn_mfma_f32_16x16x32_bf16(aq1, b1, acc[et], 0, 0, 0);
    }
    // 2) raw scores S = Q @ K^T
    f32x4 sacc[4] = {};
    #pragma unroll
    for (int kt = 0; kt < 4; ++kt) {
        bf16x8 b0 = *reinterpret_cast<const bf16x8*>(&Kl[sw(kt * 16 + cl, g * 8)]);
        bf16x8 b1 = *reinterpret_cast<const bf16x8*>(&Kl[sw(kt * 16 + cl, 32 + g * 8)]);
        sacc[kt] = __builtin_amdgcn_mfma_f32_16x16x32_bf16(aq0, b0, sacc[kt], 0, 0, 0);
        sacc[kt] = __builtin_amdgcn_mfma_f32_16x16x32_bf16(aq1, b1, sacc[kt], 0, 0, 0);
    }
    // 3) mask + 1 + alpha, den partials, stage P
    unsigned short* Pw = &Pl[w * 1024];
    float part[4] = {0.f, 0.f, 0.f, 0.f};
    #pragma unroll
    for (int kt = 0; kt < 4; ++kt) {
        int key = kt * 16 + cl;
        #pragma unroll
        for (int j = 0; j < 4; ++j) {
            int rr = g * 4 + j;
            int q = (w << 4) + rr;
            float s = (key <= q) ? fmaf(alpha, sacc[kt][j], 1.f) : 0.f;
            part[j] += s;
            Pw[rr * 64 + (key ^ ((rr & 7) << 3))] = f2b(s);
        }
    }
    #pragma unroll
    for (int j = 0; j < 4; ++j) {
        int q = (w << 4) + g * 4 + j;
        float qz = 0.f;
        #pragma unroll
        for (int m = 0; m < 4; ++m) {
            int d = cl + m * 16;
            qz = fmaf(b2f(Ql[sw(q, d)]), zp[d], qz);
        }
        part[j] += qz;
    }
    #pragma unroll
    for (int o = 1; o < 16; o <<= 1)
        #pragma unroll
        for (int j = 0; j < 4; ++j) part[j] += __shfl_xor(part[j], o);
    float invden[4];
    #pragma unroll
    for (int j = 0; j < 4; ++j) invden[j] = 1.f / ((float)(c * CHUNK) + part[j]);

    // 4) acc += P @ V
    #pragma unroll
    for (int ks = 0; ks < 2; ++ks) {
        bf16x8 ap = *reinterpret_cast<const bf16x8*>(&Pw[cl * 64 + ((ks * 32 + g * 8) ^ ((cl & 7) << 3))]);
        #pragma unroll
        for (int et = 0; et < 4; ++et) {
            bf16x8 bv = *reinterpret_cast<const bf16x8*>(&Vt[sw(et * 16 + cl, ks * 32 + g * 8)]);
            acc[et] = __builtin_amdgcn_mfma_f32_16x16x32_bf16(ap, bv, acc[et], 0, 0, 0);
        }
    }
    // 5) epilogue
    #pragma unroll
    for (int et = 0; et < 4; ++et)
        #pragma unroll
        for (int j = 0; j < 4; ++j) {
            int q = (w << 4) + g * 4 + j;
            int e = et * 16 + cl;
            float o = (vsp[e] + acc[et][j]) * invden[j];
            vhb[(size_t)(c * CHUNK + q) * (NH * DH) + h * DH + e] = f2b(o);
        }
}

// ---------------------------------------------------------------- launch
extern "C" void kernel_launch(void* const* d_in, const int* in_sizes, int n_in,
                              void* d_out, int out_size, void* d_ws, size_t ws_size,
                              hipStream_t stream) {
    const float* X  = (const float*)d_in[0];
    const float* Wq = (const float*)d_in[1];
    const float* Wk = (const float*)d_in[2];
    const float* Wv = (const float*)d_in[3];
    const float* Wo = (const float*)d_in[4];
    const float* bo = (const float*)d_in[5];
    float* out = (float*)d_out;

    char* w = (char*)d_ws;
    unsigned short* Xb   = (unsigned short*)(w);                    // 4 MiB [2048][1024]
    unsigned short* Wb   = (unsigned short*)(w + (4u  << 20));      // 6 MiB [3072][1024]
    unsigned short* Wob  = (unsigned short*)(w + (10u << 20));      // 2 MiB [1024][1024]
    unsigned short* Qb   = (unsigned short*)(w + (12u << 20));      // 12 MiB [3][16][2048][64] bf16
    unsigned short* vhb  = (unsigned short*)(w + (24u << 20));      // 4 MiB [2048][1024] bf16
    float*          nrm  = (float*)(w + (28u << 20));               // 32 f32 (max sumsq per q/k head)
    unsigned short* Ssum = (unsigned short*)(w + (29u << 20));      // 4 MiB [512][64][64] bf16
    float*          zsum = (float*)(w + (34u << 20));               // 128 KiB
    float*          vssum= (float*)(w + (34u << 20) + (1u << 17));  // 128 KiB
    unsigned short* Kb = Qb + 2097152;
    unsigned short* Vb = Qb + 2u * 2097152;

    cast_all<<<6144, 256, 0, stream>>>(X, Wq, Wk, Wv, Wo, Xb, Wb, Wob, nrm);
    gemm_qkv<<<dim3(48, 16), 256, 0, stream>>>(Xb, Wb, Qb, nrm, 1024);
    chunk_sums<<<512, 256, 0, stream>>>(Kb, Vb, Ssum, zsum, vssum);
    chunk_scan<<<264, 256, 0, stream>>>(Ssum, zsum, vssum);
    intra_attn<<<512, 256, 0, stream>>>(Qb, Kb, Vb, Ssum, zsum, vssum, nrm, vhb);
    gemm_out<<<dim3(8, 32), 256, 0, stream>>>(vhb, Wob, out, bo, 1024, 1024);
}

// Round 11
// 67.291 us; speedup vs baseline: 1.0253x; 1.0253x over previous
//
#include <hip/hip_runtime.h>

#define N_SEQ 2048
#define NH 16
#define DH 64
#define CHUNK 64
#define NCHUNK 32

typedef float f32x4 __attribute__((ext_vector_type(4)));
typedef __bf16 bf16x8 __attribute__((ext_vector_type(8)));
typedef unsigned short u16x4 __attribute__((ext_vector_type(4)));
typedef unsigned short u16x8 __attribute__((ext_vector_type(8)));

static __device__ inline unsigned short f2b(float x) {
    unsigned int u = __builtin_bit_cast(unsigned int, x);
    unsigned int r = (u + 0x7fffu + ((u >> 16) & 1u)) >> 16;  // RNE
    return (unsigned short)r;
}
static __device__ inline float b2f(unsigned short b) {
    return __builtin_bit_cast(float, (unsigned int)b << 16);
}
// swizzled elem offset in a [rows][64 bf16] LDS tile (row stride 128B)
static __device__ inline int sw(int row, int col) {
    return row * 64 + (col ^ ((row & 7) << 3));
}

// ---------------------------------------------------------------- fused casts (X + 4 weights) + zero norm buffer
__global__ __launch_bounds__(256) void cast_all(
    const float* __restrict__ X, const float* __restrict__ Wq, const float* __restrict__ Wk,
    const float* __restrict__ Wv, const float* __restrict__ Wo,
    unsigned short* __restrict__ Xb, unsigned short* __restrict__ Wb,
    unsigned short* __restrict__ Wob, float* __restrict__ nrm) {
    if (blockIdx.x == 0 && threadIdx.x < 32) nrm[threadIdx.x] = 0.f;
    int i = blockIdx.x * 256 + threadIdx.x;     // float4 id, total 1572864
    const float* src; unsigned short* dst; int off;
    if (i < 524288)       { src = X;  dst = Xb;               off = i; }
    else if (i < 786432)  { src = Wq; dst = Wb;               off = i - 524288; }
    else if (i < 1048576) { src = Wk; dst = Wb + (1u << 20);  off = i - 786432; }
    else if (i < 1310720) { src = Wv; dst = Wb + (2u << 20);  off = i - 1048576; }
    else                  { src = Wo; dst = Wob;              off = i - 1310720; }
    float4 v = reinterpret_cast<const float4*>(src)[off];
    u16x4 o;
    o[0] = f2b(v.x); o[1] = f2b(v.y); o[2] = f2b(v.z); o[3] = f2b(v.w);
    reinterpret_cast<u16x4*>(dst)[off] = o;
}

// ---------------------------------------------------------------- GEMM (bf16 MFMA, BMxBN tile, BK=64, swizzled LDS)
static __device__ inline void gload_lds16(const unsigned short* g, unsigned short* l) {
    __builtin_amdgcn_global_load_lds(
        (const __attribute__((address_space(1))) unsigned int*)g,
        (__attribute__((address_space(3))) unsigned int*)l, 16, 0, 0);
}

// MODE 0 (BM=128,BN=64): write bf16 QKV [which][h][n][d]; block owns ONE head column-group ->
//   fused per-head max row-sumsq via LDS partials + atomicMax.
// MODE 1 (BM=64,BN=128): f32 out = acc + bias
// __launch_bounds__(256,3): ~32 acc VGPRs, 25KB LDS -> 3 blocks/CU co-resident (TLP hides
// the un-pipelined stage barriers; m114: implicit wave-level overlap at ~3 blocks/CU).
template<int MODE, int BM, int BN>
__global__ __launch_bounds__(256, 3) void gemm_bf16(
    const unsigned short* __restrict__ A,
    const unsigned short* __restrict__ B,
    float* __restrict__ outf,
    unsigned short* __restrict__ outb,
    const float* __restrict__ bias,
    float* __restrict__ nrm,
    int M, int N, int K)
{
    // LDS: row stride 128B; logical 16B-slot s stored at physical p = s ^ (row&7).
    __shared__ __align__(16) unsigned short As[BM][64];
    __shared__ __align__(16) unsigned short Bs[BN][64];
    __shared__ float pnorm[2][BM];

    // XCD-aware bijective swizzle (grid count % 8 == 0), bn-major chunks
    const int L = blockIdx.y * gridDim.x + blockIdx.x;
    const int cpx = (gridDim.x * gridDim.y) >> 3;
    const int tile = (L & 7) * cpx + (L >> 3);
    const int bn = tile / gridDim.y;
    const int bm = tile % gridDim.y;

    const int t = threadIdx.x;
    const int wave = t >> 6, lane = t & 63;
    const int wm = wave >> 1, wn = wave & 1;
    const int r16 = lane & 15, ks = lane >> 4;
    constexpr int MFRAG = BM / 32;
    constexpr int NFRAG = BN / 32;

    f32x4 acc[MFRAG][NFRAG] = {};

    const unsigned short* gA = A + (size_t)bm * BM * K;
    const unsigned short* gB = B + (size_t)bn * BN * K;
    const int lrow = lane >> 3;                              // 0..7
    const int scol = (((lane & 7) ^ (lrow & 7)) << 3);       // pre-swizzled source col (elems)
    const int rsw = (r16 & 7) << 3;                          // read-side XOR (elems)

    for (int k0 = 0; k0 < K; k0 += 64) {
        __syncthreads();
        #pragma unroll
        for (int g2 = 0; g2 < BM / 32; ++g2) {
            int r0 = wave * (BM / 4) + g2 * 8;
            gload_lds16(&gA[(size_t)(r0 + lrow) * K + k0 + scol], &As[r0][0]);
        }
        #pragma unroll
        for (int g2 = 0; g2 < BN / 32; ++g2) {
            int r0 = wave * (BN / 4) + g2 * 8;
            gload_lds16(&gB[(size_t)(r0 + lrow) * K + k0 + scol], &Bs[r0][0]);
        }
        __syncthreads();

        #pragma unroll
        for (int ksub = 0; ksub < 2; ++ksub) {
            const int sl = (((ksub << 2) + ks) << 3) ^ rsw;
            bf16x8 af[MFRAG], bfr[NFRAG];
            #pragma unroll
            for (int m = 0; m < MFRAG; ++m)
                af[m] = *reinterpret_cast<const bf16x8*>(&As[wm * (BM / 2) + m * 16 + r16][sl]);
            #pragma unroll
            for (int n = 0; n < NFRAG; ++n)
                bfr[n] = *reinterpret_cast<const bf16x8*>(&Bs[wn * (BN / 2) + n * 16 + r16][sl]);
            #pragma unroll
            for (int m = 0; m < MFRAG; ++m)
                #pragma unroll
                for (int n = 0; n < NFRAG; ++n)
                    acc[m][n] = __builtin_amdgcn_mfma_f32_16x16x32_bf16(af[m], bfr[n], acc[m][n], 0, 0, 0);
        }
    }

    #pragma unroll
    for (int m = 0; m < MFRAG; ++m) {
        int row0 = bm * BM + wm * (BM / 2) + m * 16 + ks * 4;
        #pragma unroll
        for (int n = 0; n < NFRAG; ++n) {
            int col = bn * BN + wn * (BN / 2) + n * 16 + r16;
            if (MODE == 0) {
                int wch = col >> 10, h = (col >> 6) & 15, d = col & 63;
                unsigned short* dst = outb + (size_t)wch * (NH * (size_t)N_SEQ * DH)
                                          + (size_t)h * N_SEQ * DH + d;
                #pragma unroll
                for (int j = 0; j < 4; ++j)
                    dst[(size_t)(row0 + j) * DH] = f2b(acc[m][n][j]);
            } else {
                float bv = bias[col];
                #pragma unroll
                for (int j = 0; j < 4; ++j)
                    outf[(size_t)(row0 + j) * N + col] = acc[m][n][j] + bv;
            }
        }
    }

    // fused per-head max row-sumsq (MODE 0, BN=64: block owns exactly one (which, head))
    if constexpr (MODE == 0) {
        const int wch = bn >> 4;                 // bn in [0,48): 0..15 q, 16..31 k, 32..47 v
        if (wch < 2) {
            const int h = bn & 15;
            // per-wave partial row sums over its 32 columns
            #pragma unroll
            for (int m = 0; m < MFRAG; ++m)
                #pragma unroll
                for (int j = 0; j < 4; ++j) {
                    float rs = 0.f;
                    #pragma unroll
                    for (int n = 0; n < NFRAG; ++n) rs = fmaf(acc[m][n][j], acc[m][n][j], rs);
                    rs += __shfl_xor(rs, 1);
                    rs += __shfl_xor(rs, 2);
                    rs += __shfl_xor(rs, 4);
                    rs += __shfl_xor(rs, 8);
                    if (r16 == 0)
                        pnorm[wn][wm * (BM / 2) + m * 16 + ks * 4 + j] = rs;
                }
            __syncthreads();
            if (t < BM) {
                float s = pnorm[0][t] + pnorm[1][t];
                #pragma unroll
                for (int o = 1; o < 64; o <<= 1) s = fmaxf(s, __shfl_xor(s, o));
                if ((t & 63) == 0)
                    atomicMax(reinterpret_cast<unsigned int*>(&nrm[wch * 16 + h]),
                              __builtin_bit_cast(unsigned int, s));
            }
        }
    }
}

// ---------------------------------------------------------------- per-chunk sums via MFMA: S = K^T V (bf16 out), z, vs
__global__ __launch_bounds__(256) void chunk_sums(const unsigned short* __restrict__ Kb,
                                                  const unsigned short* __restrict__ Vb,
                                                  unsigned short* __restrict__ Ssum,
                                                  float* __restrict__ zsum,
                                                  float* __restrict__ vssum) {
    const int h = blockIdx.x >> 5, c = blockIdx.x & 31;
    __shared__ __align__(16) unsigned short Kt[4096];   // [d][j] swizzled (= K^T)
    __shared__ __align__(16) unsigned short Vt[4096];   // [e][j] swizzled (= V^T)
    const size_t off = ((size_t)h * N_SEQ + c * CHUNK) * DH;
    const int t = threadIdx.x, lane = t & 63;

    {   // transposed gather
        const int d = t & 63, j0 = (t >> 6) * 16;
        unsigned short rk[16], rv[16];
        #pragma unroll
        for (int i = 0; i < 16; ++i) {
            rk[i] = Kb[off + (size_t)(j0 + i) * DH + d];
            rv[i] = Vb[off + (size_t)(j0 + i) * DH + d];
        }
        u16x8 a, b;
        #pragma unroll
        for (int i = 0; i < 8; ++i) { a[i] = rk[i]; b[i] = rk[8 + i]; }
        *reinterpret_cast<u16x8*>(&Kt[sw(d, j0)]) = a;
        *reinterpret_cast<u16x8*>(&Kt[sw(d, j0 + 8)]) = b;
        #pragma unroll
        for (int i = 0; i < 8; ++i) { a[i] = rv[i]; b[i] = rv[8 + i]; }
        *reinterpret_cast<u16x8*>(&Vt[sw(d, j0)]) = a;
        *reinterpret_cast<u16x8*>(&Vt[sw(d, j0 + 8)]) = b;
    }
    __syncthreads();

    const int w = t >> 6, cl = lane & 15, g = lane >> 4;
    bf16x8 ak0 = *reinterpret_cast<const bf16x8*>(&Kt[sw(w * 16 + cl, g * 8)]);
    bf16x8 ak1 = *reinterpret_cast<const bf16x8*>(&Kt[sw(w * 16 + cl, 32 + g * 8)]);
    f32x4 acc[4] = {};
    #pragma unroll
    for (int et = 0; et < 4; ++et) {
        bf16x8 b0 = *reinterpret_cast<const bf16x8*>(&Vt[sw(et * 16 + cl, g * 8)]);
        bf16x8 b1 = *reinterpret_cast<const bf16x8*>(&Vt[sw(et * 16 + cl, 32 + g * 8)]);
        acc[et] = __builtin_amdgcn_mfma_f32_16x16x32_bf16(ak0, b0, acc[et], 0, 0, 0);
        acc[et] = __builtin_amdgcn_mfma_f32_16x16x32_bf16(ak1, b1, acc[et], 0, 0, 0);
    }
    unsigned short* So = Ssum + (size_t)blockIdx.x * (DH * DH);
    #pragma unroll
    for (int et = 0; et < 4; ++et)
        #pragma unroll
        for (int j = 0; j < 4; ++j)
            So[(size_t)(w * 16 + g * 4 + j) * DH + et * 16 + cl] = f2b(acc[et][j]);

    if (t < 64) {
        float z = 0.f;
        #pragma unroll
        for (int i = 0; i < 8; ++i) {
            u16x8 v = *reinterpret_cast<const u16x8*>(&Kt[sw(t, i * 8)]);
            #pragma unroll
            for (int k = 0; k < 8; ++k) z += b2f(v[k]);
        }
        zsum[(size_t)blockIdx.x * DH + t] = z;
    } else if (t < 128) {
        int e = t - 64;
        float z = 0.f;
        #pragma unroll
        for (int i = 0; i < 8; ++i) {
            u16x8 v = *reinterpret_cast<const u16x8*>(&Vt[sw(e, i * 8)]);
            #pragma unroll
            for (int k = 0; k < 8; ++k) z += b2f(v[k]);
        }
        vssum[(size_t)blockIdx.x * DH + e] = z;
    }
}

// ---------------------------------------------------------------- exclusive scan over chunks (f32 run, bf16 in-place)
__global__ __launch_bounds__(256) void chunk_scan(unsigned short* __restrict__ Ssum,
                                                  float* __restrict__ zsum,
                                                  float* __restrict__ vssum) {
    const int b = blockIdx.x;
    if (b < 256) {
        const int h = b >> 4;
        const int e = (b & 15) * 256 + threadIdx.x;
        size_t base = (size_t)h * NCHUNK * (DH * DH) + e;
        float run = 0.f;
        for (int c = 0; c < NCHUNK; ++c) {
            size_t idx = base + (size_t)c * (DH * DH);
            float tmp = b2f(Ssum[idx]); Ssum[idx] = f2b(run); run += tmp;
        }
    } else {
        const int g = (b - 256) * 256 + threadIdx.x;
        const int which = g >> 10, h = (g >> 6) & 15, e = g & 63;
        float* arr = which ? vssum : zsum;
        size_t base = (size_t)h * NCHUNK * DH + e;
        float run = 0.f;
        for (int c = 0; c < NCHUNK; ++c) {
            size_t idx = base + (size_t)c * DH;
            float tmp = arr[idx]; arr[idx] = run; run += tmp;
        }
    }
}

// ---------------------------------------------------------------- intra-chunk attention + combine, MFMA
__global__ __launch_bounds__(256) void intra_attn(
    const unsigned short* __restrict__ Qb, const unsigned short* __restrict__ Kb,
    const unsigned short* __restrict__ Vb,
    const unsigned short* __restrict__ Ssum, const float* __restrict__ zsum,
    const float* __restrict__ vssum, const float* __restrict__ nrm,
    unsigned short* __restrict__ vhb) {
    const int h = blockIdx.x >> 5, c = blockIdx.x & 31;
    __shared__ __align__(16) unsigned short Ql[4096];   // [q][d] swizzled
    __shared__ __align__(16) unsigned short Kl[4096];   // [key][d] swizzled
    __shared__ __align__(16) unsigned short Vt[4096];   // [e][key] swizzled
    __shared__ __align__(16) unsigned short Sp[4096];   // [e][d] = bf16(alpha*S_prev[d][e]) swizzled
    __shared__ __align__(16) unsigned short Pl[4096];   // per-wave [16][64] swizzled
    __shared__ float zp[DH], vsp[DH];

    const int t = threadIdx.x, lane = t & 63, w = t >> 6;
    const float alpha = 1.f / sqrtf(nrm[h] * nrm[16 + h]);   // 1/(qn*kn), nrm = max sumsq
    const size_t off = ((size_t)h * N_SEQ + c * CHUNK) * DH;

    // Q, K: row-major coalesced loads, swizzled 16B writes
    #pragma unroll
    for (int p = 0; p < 2; ++p) {
        int lin = t + p * 256;
        int row = lin >> 3, col = (lin & 7) * 8;
        u16x8 q = *reinterpret_cast<const u16x8*>(Qb + off + (size_t)row * DH + col);
        u16x8 k = *reinterpret_cast<const u16x8*>(Kb + off + (size_t)row * DH + col);
        *reinterpret_cast<u16x8*>(&Ql[sw(row, col)]) = q;
        *reinterpret_cast<u16x8*>(&Kl[sw(row, col)]) = k;
    }
    // V transposed gather
    {
        const int e = t & 63, j0 = (t >> 6) * 16;
        unsigned short rv[16];
        #pragma unroll
        for (int i = 0; i < 16; ++i) rv[i] = Vb[off + (size_t)(j0 + i) * DH + e];
        u16x8 a, b;
        #pragma unroll
        for (int i = 0; i < 8; ++i) { a[i] = rv[i]; b[i] = rv[8 + i]; }
        *reinterpret_cast<u16x8*>(&Vt[sw(e, j0)]) = a;
        *reinterpret_cast<u16x8*>(&Vt[sw(e, j0 + 8)]) = b;
    }
    // S_prev transposed gather (bf16 in), alpha-prescaled
    {
        const unsigned short* Sg = Ssum + (size_t)blockIdx.x * (DH * DH);
        const int e = t & 63, d0 = (t >> 6) * 16;
        u16x8 a, b;
        #pragma unroll
        for (int i = 0; i < 8; ++i) a[i] = f2b(alpha * b2f(Sg[(size_t)(d0 + i) * DH + e]));
        #pragma unroll
        for (int i = 0; i < 8; ++i) b[i] = f2b(alpha * b2f(Sg[(size_t)(d0 + 8 + i) * DH + e]));
        *reinterpret_cast<u16x8*>(&Sp[sw(e, d0)]) = a;
        *reinterpret_cast<u16x8*>(&Sp[sw(e, d0 + 8)]) = b;
    }
    if (t < 64) zp[t] = alpha * zsum[(size_t)blockIdx.x * DH + t];
    else if (t < 128) vsp[t - 64] = vssum[(size_t)blockIdx.x * DH + (t - 64)];
    __syncthreads();

    const int cl = lane & 15, g = lane >> 4;
    const int qrow = (w << 4) + cl;

    bf16x8 aq0 = *reinterpret_cast<const bf16x8*>(&Ql[sw(qrow, g * 8)]);
    bf16x8 aq1 = *reinterpret_cast<const bf16x8*>(&Ql[sw(qrow, 32 + g * 8)]);

    // 1) acc = Q @ (alpha*S_prev)
    f32x4 acc[4] = {};
    #pragma unroll
    for (int et = 0; et < 4; ++et) {
        bf16x8 b0 = *reinterpret_cast<const bf16x8*>(&Sp[sw(et * 16 + cl, g * 8)]);
        bf16x8 b1 = *reinterpret_cast<const bf16x8*>(&Sp[sw(et * 16 + cl, 32 + g * 8)]);
        acc[et] = __builtin_amdgcn_mfma_f32_16x16x32_bf16(aq0, b0, acc[et], 0, 0, 0);
        acc[et] = __builtin_amdgcn_mfma_f32_16x16x32_bf16(aq1, b1, acc[et], 0, 0, 0);
    }
    // 2) raw scores S = Q @ K^T
    f32x4 sacc[4] = {};
    #pragma unroll
    for (int kt = 0; kt < 4; ++kt) {
        bf16x8 b0 = *reinterpret_cast<const bf16x8*>(&Kl[sw(kt * 16 + cl, g * 8)]);
        bf16x8 b1 = *reinterpret_cast<const bf16x8*>(&Kl[sw(kt * 16 + cl, 32 + g * 8)]);
        sacc[kt] = __builtin_amdgcn_mfma_f32_16x16x32_bf16(aq0, b0, sacc[kt], 0, 0, 0);
        sacc[kt] = __builtin_amdgcn_mfma_f32_16x16x32_bf16(aq1, b1, sacc[kt], 0, 0, 0);
    }
    // 3) mask + 1 + alpha, den partials, stage P
    unsigned short* Pw = &Pl[w * 1024];
    float part[4] = {0.f, 0.f, 0.f, 0.f};
    #pragma unroll
    for (int kt = 0; kt < 4; ++kt) {
        int key = kt * 16 + cl;
        #pragma unroll
        for (int j = 0; j < 4; ++j) {
            int rr = g * 4 + j;
            int q = (w << 4) + rr;
            float s = (key <= q) ? fmaf(alpha, sacc[kt][j], 1.f) : 0.f;
            part[j] += s;
            Pw[rr * 64 + (key ^ ((rr & 7) << 3))] = f2b(s);
        }
    }
    #pragma unroll
    for (int j = 0; j < 4; ++j) {
        int q = (w << 4) + g * 4 + j;
        float qz = 0.f;
        #pragma unroll
        for (int m = 0; m < 4; ++m) {
            int d = cl + m * 16;
            qz = fmaf(b2f(Ql[sw(q, d)]), zp[d], qz);
        }
        part[j] += qz;
    }
    #pragma unroll
    for (int o = 1; o < 16; o <<= 1)
        #pragma unroll
        for (int j = 0; j < 4; ++j) part[j] += __shfl_xor(part[j], o);
    float invden[4];
    #pragma unroll
    for (int j = 0; j < 4; ++j) invden[j] = 1.f / ((float)(c * CHUNK) + part[j]);

    // 4) acc += P @ V
    #pragma unroll
    for (int ks = 0; ks < 2; ++ks) {
        bf16x8 ap = *reinterpret_cast<const bf16x8*>(&Pw[cl * 64 + ((ks * 32 + g * 8) ^ ((cl & 7) << 3))]);
        #pragma unroll
        for (int et = 0; et < 4; ++et) {
            bf16x8 bv = *reinterpret_cast<const bf16x8*>(&Vt[sw(et * 16 + cl, ks * 32 + g * 8)]);
            acc[et] = __builtin_amdgcn_mfma_f32_16x16x32_bf16(ap, bv, acc[et], 0, 0, 0);
        }
    }
    // 5) epilogue
    #pragma unroll
    for (int et = 0; et < 4; ++et)
        #pragma unroll
        for (int j = 0; j < 4; ++j) {
            int q = (w << 4) + g * 4 + j;
            int e = et * 16 + cl;
            float o = (vsp[e] + acc[et][j]) * invden[j];
            vhb[(size_t)(c * CHUNK + q) * (NH * DH) + h * DH + e] = f2b(o);
        }
}

// ---------------------------------------------------------------- launch
extern "C" void kernel_launch(void* const* d_in, const int* in_sizes, int n_in,
                              void* d_out, int out_size, void* d_ws, size_t ws_size,
                              hipStream_t stream) {
    const float* X  = (const float*)d_in[0];
    const float* Wq = (const float*)d_in[1];
    const float* Wk = (const float*)d_in[2];
    const float* Wv = (const float*)d_in[3];
    const float* Wo = (const float*)d_in[4];
    const float* bo = (const float*)d_in[5];
    float* out = (float*)d_out;

    char* w = (char*)d_ws;
    unsigned short* Xb   = (unsigned short*)(w);                    // 4 MiB [2048][1024]
    unsigned short* Wb   = (unsigned short*)(w + (4u  << 20));      // 6 MiB [3072][1024]
    unsigned short* Wob  = (unsigned short*)(w + (10u << 20));      // 2 MiB [1024][1024]
    unsigned short* Qb   = (unsigned short*)(w + (12u << 20));      // 12 MiB [3][16][2048][64] bf16
    unsigned short* vhb  = (unsigned short*)(w + (24u << 20));      // 4 MiB [2048][1024] bf16
    float*          nrm  = (float*)(w + (28u << 20));               // 32 f32 (max sumsq per q/k head)
    unsigned short* Ssum = (unsigned short*)(w + (29u << 20));      // 4 MiB [512][64][64] bf16
    float*          zsum = (float*)(w + (34u << 20));               // 128 KiB
    float*          vssum= (float*)(w + (34u << 20) + (1u << 17));  // 128 KiB
    unsigned short* Kb = Qb + 2097152;
    unsigned short* Vb = Qb + 2u * 2097152;

    cast_all<<<6144, 256, 0, stream>>>(X, Wq, Wk, Wv, Wo, Xb, Wb, Wob, nrm);
    gemm_bf16<0, 128, 64><<<dim3(48, 16), 256, 0, stream>>>(Xb, Wb, nullptr, Qb, nullptr, nrm, 2048, 3072, 1024);
    chunk_sums<<<512, 256, 0, stream>>>(Kb, Vb, Ssum, zsum, vssum);
    chunk_scan<<<264, 256, 0, stream>>>(Ssum, zsum, vssum);
    intra_attn<<<512, 256, 0, stream>>>(Qb, Kb, Vb, Ssum, zsum, vssum, nrm, vhb);
    gemm_bf16<1, 64, 128><<<dim3(8, 32), 256, 0, stream>>>(vhb, Wob, out, nullptr, bo, nullptr, 2048, 1024, 1024);
}

// Round 12
// 63.490 us; speedup vs baseline: 1.0867x; 1.0599x over previous
//
#include <hip/hip_runtime.h>

#define N_SEQ 2048
#define NH 16
#define DH 64
#define CHUNK 64
#define NCHUNK 32

typedef float f32x4 __attribute__((ext_vector_type(4)));
typedef __bf16 bf16x8 __attribute__((ext_vector_type(8)));
typedef unsigned short u16x4 __attribute__((ext_vector_type(4)));
typedef unsigned short u16x8 __attribute__((ext_vector_type(8)));

static __device__ inline unsigned short f2b(float x) {
    unsigned int u = __builtin_bit_cast(unsigned int, x);
    unsigned int r = (u + 0x7fffu + ((u >> 16) & 1u)) >> 16;  // RNE
    return (unsigned short)r;
}
static __device__ inline float b2f(unsigned short b) {
    return __builtin_bit_cast(float, (unsigned int)b << 16);
}
// swizzled elem offset in a [rows][64 bf16] LDS tile (row stride 128B)
static __device__ inline int sw(int row, int col) {
    return row * 64 + (col ^ ((row & 7) << 3));
}

// ---------------------------------------------------------------- fused casts (X + 4 weights) + zero norm buffer
__global__ __launch_bounds__(256) void cast_all(
    const float* __restrict__ X, const float* __restrict__ Wq, const float* __restrict__ Wk,
    const float* __restrict__ Wv, const float* __restrict__ Wo,
    unsigned short* __restrict__ Xb, unsigned short* __restrict__ Wb,
    unsigned short* __restrict__ Wob, float* __restrict__ nrm) {
    if (blockIdx.x == 0 && threadIdx.x < 32) nrm[threadIdx.x] = 0.f;
    int i = blockIdx.x * 256 + threadIdx.x;     // float4 id, total 1572864
    const float* src; unsigned short* dst; int off;
    if (i < 524288)       { src = X;  dst = Xb;               off = i; }
    else if (i < 786432)  { src = Wq; dst = Wb;               off = i - 524288; }
    else if (i < 1048576) { src = Wk; dst = Wb + (1u << 20);  off = i - 786432; }
    else if (i < 1310720) { src = Wv; dst = Wb + (2u << 20);  off = i - 1048576; }
    else                  { src = Wo; dst = Wob;              off = i - 1310720; }
    float4 v = reinterpret_cast<const float4*>(src)[off];
    u16x4 o;
    o[0] = f2b(v.x); o[1] = f2b(v.y); o[2] = f2b(v.z); o[3] = f2b(v.w);
    reinterpret_cast<u16x4*>(dst)[off] = o;
}

// ---------------------------------------------------------------- GEMM (bf16 MFMA, BMxBN tile, BK-deep LDS, swizzled)
static __device__ inline void gload_lds16(const unsigned short* g, unsigned short* l) {
    __builtin_amdgcn_global_load_lds(
        (const __attribute__((address_space(1))) unsigned int*)g,
        (__attribute__((address_space(3))) unsigned int*)l, 16, 0, 0);
}

// MODE 0 (BM=128,BN=64): write bf16 QKV [which][h][n][d]; block owns ONE head column-group ->
//   fused per-head max row-sumsq via LDS partials + atomicMax.
// MODE 1 (BM=64,BN=128): f32 out = acc + bias
// BK=128: 8 K-steps (vs 16) -> half the vmcnt(0)+barrier drains; 48KB LDS keeps 3 blocks/CU
// (m132's BK=128 regression was the 64KB/2-block case — doesn't apply to these tile shapes).
template<int MODE, int BM, int BN, int BK>
__global__ __launch_bounds__(256, 3) void gemm_bf16(
    const unsigned short* __restrict__ A,
    const unsigned short* __restrict__ B,
    float* __restrict__ outf,
    unsigned short* __restrict__ outb,
    const float* __restrict__ bias,
    float* __restrict__ nrm,
    int M, int N, int K)
{
    // LDS: row = BK bf16 (BK/8 16B-slots); logical slot s of row r stored at phys p = s ^ (r&7).
    // Granule class = p&7 (row-independent since BK/8 % 8 == 0) -> 16-lane fragment reads span
    // all 8 classes (2 lanes/class = conflict-free).
    __shared__ __align__(16) unsigned short As[BM][BK];
    __shared__ __align__(16) unsigned short Bs[BN][BK];
    __shared__ float pnorm[2][BM];

    constexpr int SLOTS = BK / 8;            // 16B-slots per row
    constexpr int RPL   = 64 / SLOTS;        // rows covered per gload (64 lanes x 16B)

    // XCD-aware bijective swizzle (grid count % 8 == 0), bn-major chunks
    const int L = blockIdx.y * gridDim.x + blockIdx.x;
    const int cpx = (gridDim.x * gridDim.y) >> 3;
    const int tile = (L & 7) * cpx + (L >> 3);
    const int bn = tile / gridDim.y;
    const int bm = tile % gridDim.y;

    const int t = threadIdx.x;
    const int wave = t >> 6, lane = t & 63;
    const int wm = wave >> 1, wn = wave & 1;
    const int r16 = lane & 15, ks = lane >> 4;
    constexpr int MFRAG = BM / 32;
    constexpr int NFRAG = BN / 32;

    f32x4 acc[MFRAG][NFRAG] = {};

    const unsigned short* gA = A + (size_t)bm * BM * K;
    const unsigned short* gB = B + (size_t)bn * BN * K;
    const int lrow  = lane / SLOTS;                          // row within gload group
    const int lslot = lane % SLOTS;                          // phys 16B-slot within row
    const int rsw = (r16 & 7);                               // read-side XOR (slot units)

    for (int k0 = 0; k0 < K; k0 += BK) {
        __syncthreads();
        #pragma unroll
        for (int g2 = 0; g2 < BM * SLOTS / 256; ++g2) {
            int r0 = wave * (BM / 4) + g2 * RPL;
            int srccol = ((lslot ^ ((r0 + lrow) & 7)) << 3);   // pre-swizzled source col
            gload_lds16(&gA[(size_t)(r0 + lrow) * K + k0 + srccol], &As[r0][0]);
        }
        #pragma unroll
        for (int g2 = 0; g2 < BN * SLOTS / 256; ++g2) {
            int r0 = wave * (BN / 4) + g2 * RPL;
            int srccol = ((lslot ^ ((r0 + lrow) & 7)) << 3);
            gload_lds16(&gB[(size_t)(r0 + lrow) * K + k0 + srccol], &Bs[r0][0]);
        }
        __syncthreads();

        #pragma unroll
        for (int kk = 0; kk < BK / 32; ++kk) {
            const int sl = ((((kk << 2) + ks) ^ rsw) << 3);   // swizzled elem offset
            bf16x8 af[MFRAG], bfr[NFRAG];
            #pragma unroll
            for (int m = 0; m < MFRAG; ++m)
                af[m] = *reinterpret_cast<const bf16x8*>(&As[wm * (BM / 2) + m * 16 + r16][sl]);
            #pragma unroll
            for (int n = 0; n < NFRAG; ++n)
                bfr[n] = *reinterpret_cast<const bf16x8*>(&Bs[wn * (BN / 2) + n * 16 + r16][sl]);
            #pragma unroll
            for (int m = 0; m < MFRAG; ++m)
                #pragma unroll
                for (int n = 0; n < NFRAG; ++n)
                    acc[m][n] = __builtin_amdgcn_mfma_f32_16x16x32_bf16(af[m], bfr[n], acc[m][n], 0, 0, 0);
        }
    }

    #pragma unroll
    for (int m = 0; m < MFRAG; ++m) {
        int row0 = bm * BM + wm * (BM / 2) + m * 16 + ks * 4;
        #pragma unroll
        for (int n = 0; n < NFRAG; ++n) {
            int col = bn * BN + wn * (BN / 2) + n * 16 + r16;
            if (MODE == 0) {
                int wch = col >> 10, h = (col >> 6) & 15, d = col & 63;
                unsigned short* dst = outb + (size_t)wch * (NH * (size_t)N_SEQ * DH)
                                          + (size_t)h * N_SEQ * DH + d;
                #pragma unroll
                for (int j = 0; j < 4; ++j)
                    dst[(size_t)(row0 + j) * DH] = f2b(acc[m][n][j]);
            } else {
                float bv = bias[col];
                #pragma unroll
                for (int j = 0; j < 4; ++j)
                    outf[(size_t)(row0 + j) * N + col] = acc[m][n][j] + bv;
            }
        }
    }

    // fused per-head max row-sumsq (MODE 0, BN=64: block owns exactly one (which, head))
    if constexpr (MODE == 0) {
        const int wch = bn >> 4;                 // bn in [0,48): 0..15 q, 16..31 k, 32..47 v
        if (wch < 2) {
            const int h = bn & 15;
            #pragma unroll
            for (int m = 0; m < MFRAG; ++m)
                #pragma unroll
                for (int j = 0; j < 4; ++j) {
                    float rs = 0.f;
                    #pragma unroll
                    for (int n = 0; n < NFRAG; ++n) rs = fmaf(acc[m][n][j], acc[m][n][j], rs);
                    rs += __shfl_xor(rs, 1);
                    rs += __shfl_xor(rs, 2);
                    rs += __shfl_xor(rs, 4);
                    rs += __shfl_xor(rs, 8);
                    if (r16 == 0)
                        pnorm[wn][wm * (BM / 2) + m * 16 + ks * 4 + j] = rs;
                }
            __syncthreads();
            if (t < BM) {
                float s = pnorm[0][t] + pnorm[1][t];
                #pragma unroll
                for (int o = 1; o < 64; o <<= 1) s = fmaxf(s, __shfl_xor(s, o));
                if ((t & 63) == 0)
                    atomicMax(reinterpret_cast<unsigned int*>(&nrm[wch * 16 + h]),
                              __builtin_bit_cast(unsigned int, s));
            }
        }
    }
}

// ---------------------------------------------------------------- per-chunk sums via MFMA: S = K^T V (bf16 out), z, vs
__global__ __launch_bounds__(256) void chunk_sums(const unsigned short* __restrict__ Kb,
                                                  const unsigned short* __restrict__ Vb,
                                                  unsigned short* __restrict__ Ssum,
                                                  float* __restrict__ zsum,
                                                  float* __restrict__ vssum) {
    const int h = blockIdx.x >> 5, c = blockIdx.x & 31;
    __shared__ __align__(16) unsigned short Kt[4096];   // [d][j] swizzled (= K^T)
    __shared__ __align__(16) unsigned short Vt[4096];   // [e][j] swizzled (= V^T)
    const size_t off = ((size_t)h * N_SEQ + c * CHUNK) * DH;
    const int t = threadIdx.x, lane = t & 63;

    {   // transposed gather
        const int d = t & 63, j0 = (t >> 6) * 16;
        unsigned short rk[16], rv[16];
        #pragma unroll
        for (int i = 0; i < 16; ++i) {
            rk[i] = Kb[off + (size_t)(j0 + i) * DH + d];
            rv[i] = Vb[off + (size_t)(j0 + i) * DH + d];
        }
        u16x8 a, b;
        #pragma unroll
        for (int i = 0; i < 8; ++i) { a[i] = rk[i]; b[i] = rk[8 + i]; }
        *reinterpret_cast<u16x8*>(&Kt[sw(d, j0)]) = a;
        *reinterpret_cast<u16x8*>(&Kt[sw(d, j0 + 8)]) = b;
        #pragma unroll
        for (int i = 0; i < 8; ++i) { a[i] = rv[i]; b[i] = rv[8 + i]; }
        *reinterpret_cast<u16x8*>(&Vt[sw(d, j0)]) = a;
        *reinterpret_cast<u16x8*>(&Vt[sw(d, j0 + 8)]) = b;
    }
    __syncthreads();

    const int w = t >> 6, cl = lane & 15, g = lane >> 4;
    bf16x8 ak0 = *reinterpret_cast<const bf16x8*>(&Kt[sw(w * 16 + cl, g * 8)]);
    bf16x8 ak1 = *reinterpret_cast<const bf16x8*>(&Kt[sw(w * 16 + cl, 32 + g * 8)]);
    f32x4 acc[4] = {};
    #pragma unroll
    for (int et = 0; et < 4; ++et) {
        bf16x8 b0 = *reinterpret_cast<const bf16x8*>(&Vt[sw(et * 16 + cl, g * 8)]);
        bf16x8 b1 = *reinterpret_cast<const bf16x8*>(&Vt[sw(et * 16 + cl, 32 + g * 8)]);
        acc[et] = __builtin_amdgcn_mfma_f32_16x16x32_bf16(ak0, b0, acc[et], 0, 0, 0);
        acc[et] = __builtin_amdgcn_mfma_f32_16x16x32_bf16(ak1, b1, acc[et], 0, 0, 0);
    }
    unsigned short* So = Ssum + (size_t)blockIdx.x * (DH * DH);
    #pragma unroll
    for (int et = 0; et < 4; ++et)
        #pragma unroll
        for (int j = 0; j < 4; ++j)
            So[(size_t)(w * 16 + g * 4 + j) * DH + et * 16 + cl] = f2b(acc[et][j]);

    if (t < 64) {
        float z = 0.f;
        #pragma unroll
        for (int i = 0; i < 8; ++i) {
            u16x8 v = *reinterpret_cast<const u16x8*>(&Kt[sw(t, i * 8)]);
            #pragma unroll
            for (int k = 0; k < 8; ++k) z += b2f(v[k]);
        }
        zsum[(size_t)blockIdx.x * DH + t] = z;
    } else if (t < 128) {
        int e = t - 64;
        float z = 0.f;
        #pragma unroll
        for (int i = 0; i < 8; ++i) {
            u16x8 v = *reinterpret_cast<const u16x8*>(&Vt[sw(e, i * 8)]);
            #pragma unroll
            for (int k = 0; k < 8; ++k) z += b2f(v[k]);
        }
        vssum[(size_t)blockIdx.x * DH + e] = z;
    }
}

// ---------------------------------------------------------------- exclusive scan over chunks (f32 run, bf16 in-place)
__global__ __launch_bounds__(256) void chunk_scan(unsigned short* __restrict__ Ssum,
                                                  float* __restrict__ zsum,
                                                  float* __restrict__ vssum) {
    const int b = blockIdx.x;
    if (b < 256) {
        const int h = b >> 4;
        const int e = (b & 15) * 256 + threadIdx.x;
        size_t base = (size_t)h * NCHUNK * (DH * DH) + e;
        float run = 0.f;
        for (int c = 0; c < NCHUNK; ++c) {
            size_t idx = base + (size_t)c * (DH * DH);
            float tmp = b2f(Ssum[idx]); Ssum[idx] = f2b(run); run += tmp;
        }
    } else {
        const int g = (b - 256) * 256 + threadIdx.x;
        const int which = g >> 10, h = (g >> 6) & 15, e = g & 63;
        float* arr = which ? vssum : zsum;
        size_t base = (size_t)h * NCHUNK * DH + e;
        float run = 0.f;
        for (int c = 0; c < NCHUNK; ++c) {
            size_t idx = base + (size_t)c * DH;
            float tmp = arr[idx]; arr[idx] = run; run += tmp;
        }
    }
}

// ---------------------------------------------------------------- intra-chunk attention + combine, MFMA
__global__ __launch_bounds__(256) void intra_attn(
    const unsigned short* __restrict__ Qb, const unsigned short* __restrict__ Kb,
    const unsigned short* __restrict__ Vb,
    const unsigned short* __restrict__ Ssum, const float* __restrict__ zsum,
    const float* __restrict__ vssum, const float* __restrict__ nrm,
    unsigned short* __restrict__ vhb) {
    const int h = blockIdx.x >> 5, c = blockIdx.x & 31;
    __shared__ __align__(16) unsigned short Ql[4096];   // [q][d] swizzled
    __shared__ __align__(16) unsigned short Kl[4096];   // [key][d] swizzled
    __shared__ __align__(16) unsigned short Vt[4096];   // [e][key] swizzled
    __shared__ __align__(16) unsigned short Sp[4096];   // [e][d] = bf16(alpha*S_prev[d][e]) swizzled
    __shared__ __align__(16) unsigned short Pl[4096];   // per-wave [16][64] swizzled
    __shared__ float zp[DH], vsp[DH];

    const int t = threadIdx.x, lane = t & 63, w = t >> 6;
    const float alpha = 1.f / sqrtf(nrm[h] * nrm[16 + h]);   // 1/(qn*kn), nrm = max sumsq
    const size_t off = ((size_t)h * N_SEQ + c * CHUNK) * DH;

    // Q, K: row-major coalesced loads, swizzled 16B writes
    #pragma unroll
    for (int p = 0; p < 2; ++p) {
        int lin = t + p * 256;
        int row = lin >> 3, col = (lin & 7) * 8;
        u16x8 q = *reinterpret_cast<const u16x8*>(Qb + off + (size_t)row * DH + col);
        u16x8 k = *reinterpret_cast<const u16x8*>(Kb + off + (size_t)row * DH + col);
        *reinterpret_cast<u16x8*>(&Ql[sw(row, col)]) = q;
        *reinterpret_cast<u16x8*>(&Kl[sw(row, col)]) = k;
    }
    // V transposed gather
    {
        const int e = t & 63, j0 = (t >> 6) * 16;
        unsigned short rv[16];
        #pragma unroll
        for (int i = 0; i < 16; ++i) rv[i] = Vb[off + (size_t)(j0 + i) * DH + e];
        u16x8 a, b;
        #pragma unroll
        for (int i = 0; i < 8; ++i) { a[i] = rv[i]; b[i] = rv[8 + i]; }
        *reinterpret_cast<u16x8*>(&Vt[sw(e, j0)]) = a;
        *reinterpret_cast<u16x8*>(&Vt[sw(e, j0 + 8)]) = b;
    }
    // S_prev transposed gather (bf16 in), alpha-prescaled
    {
        const unsigned short* Sg = Ssum + (size_t)blockIdx.x * (DH * DH);
        const int e = t & 63, d0 = (t >> 6) * 16;
        u16x8 a, b;
        #pragma unroll
        for (int i = 0; i < 8; ++i) a[i] = f2b(alpha * b2f(Sg[(size_t)(d0 + i) * DH + e]));
        #pragma unroll
        for (int i = 0; i < 8; ++i) b[i] = f2b(alpha * b2f(Sg[(size_t)(d0 + 8 + i) * DH + e]));
        *reinterpret_cast<u16x8*>(&Sp[sw(e, d0)]) = a;
        *reinterpret_cast<u16x8*>(&Sp[sw(e, d0 + 8)]) = b;
    }
    if (t < 64) zp[t] = alpha * zsum[(size_t)blockIdx.x * DH + t];
    else if (t < 128) vsp[t - 64] = vssum[(size_t)blockIdx.x * DH + (t - 64)];
    __syncthreads();

    const int cl = lane & 15, g = lane >> 4;
    const int qrow = (w << 4) + cl;

    bf16x8 aq0 = *reinterpret_cast<const bf16x8*>(&Ql[sw(qrow, g * 8)]);
    bf16x8 aq1 = *reinterpret_cast<const bf16x8*>(&Ql[sw(qrow, 32 + g * 8)]);

    // 1) acc = Q @ (alpha*S_prev)
    f32x4 acc[4] = {};
    #pragma unroll
    for (int et = 0; et < 4; ++et) {
        bf16x8 b0 = *reinterpret_cast<const bf16x8*>(&Sp[sw(et * 16 + cl, g * 8)]);
        bf16x8 b1 = *reinterpret_cast<const bf16x8*>(&Sp[sw(et * 16 + cl, 32 + g * 8)]);
        acc[et] = __builtin_amdgcn_mfma_f32_16x16x32_bf16(aq0, b0, acc[et], 0, 0, 0);
        acc[et] = __builtin_amdgcn_mfma_f32_16x16x32_bf16(aq1, b1, acc[et], 0, 0, 0);
    }
    // 2) raw scores S = Q @ K^T
    f32x4 sacc[4] = {};
    #pragma unroll
    for (int kt = 0; kt < 4; ++kt) {
        bf16x8 b0 = *reinterpret_cast<const bf16x8*>(&Kl[sw(kt * 16 + cl, g * 8)]);
        bf16x8 b1 = *reinterpret_cast<const bf16x8*>(&Kl[sw(kt * 16 + cl, 32 + g * 8)]);
        sacc[kt] = __builtin_amdgcn_mfma_f32_16x16x32_bf16(aq0, b0, sacc[kt], 0, 0, 0);
        sacc[kt] = __builtin_amdgcn_mfma_f32_16x16x32_bf16(aq1, b1, sacc[kt], 0, 0, 0);
    }
    // 3) mask + 1 + alpha, den partials, stage P
    unsigned short* Pw = &Pl[w * 1024];
    float part[4] = {0.f, 0.f, 0.f, 0.f};
    #pragma unroll
    for (int kt = 0; kt < 4; ++kt) {
        int key = kt * 16 + cl;
        #pragma unroll
        for (int j = 0; j < 4; ++j) {
            int rr = g * 4 + j;
            int q = (w << 4) + rr;
            float s = (key <= q) ? fmaf(alpha, sacc[kt][j], 1.f) : 0.f;
            part[j] += s;
            Pw[rr * 64 + (key ^ ((rr & 7) << 3))] = f2b(s);
        }
    }
    #pragma unroll
    for (int j = 0; j < 4; ++j) {
        int q = (w << 4) + g * 4 + j;
        float qz = 0.f;
        #pragma unroll
        for (int m = 0; m < 4; ++m) {
            int d = cl + m * 16;
            qz = fmaf(b2f(Ql[sw(q, d)]), zp[d], qz);
        }
        part[j] += qz;
    }
    #pragma unroll
    for (int o = 1; o < 16; o <<= 1)
        #pragma unroll
        for (int j = 0; j < 4; ++j) part[j] += __shfl_xor(part[j], o);
    float invden[4];
    #pragma unroll
    for (int j = 0; j < 4; ++j) invden[j] = 1.f / ((float)(c * CHUNK) + part[j]);

    // 4) acc += P @ V
    #pragma unroll
    for (int ks = 0; ks < 2; ++ks) {
        bf16x8 ap = *reinterpret_cast<const bf16x8*>(&Pw[cl * 64 + ((ks * 32 + g * 8) ^ ((cl & 7) << 3))]);
        #pragma unroll
        for (int et = 0; et < 4; ++et) {
            bf16x8 bv = *reinterpret_cast<const bf16x8*>(&Vt[sw(et * 16 + cl, ks * 32 + g * 8)]);
            acc[et] = __builtin_amdgcn_mfma_f32_16x16x32_bf16(ap, bv, acc[et], 0, 0, 0);
        }
    }
    // 5) epilogue
    #pragma unroll
    for (int et = 0; et < 4; ++et)
        #pragma unroll
        for (int j = 0; j < 4; ++j) {
            int q = (w << 4) + g * 4 + j;
            int e = et * 16 + cl;
            float o = (vsp[e] + acc[et][j]) * invden[j];
            vhb[(size_t)(c * CHUNK + q) * (NH * DH) + h * DH + e] = f2b(o);
        }
}

// ---------------------------------------------------------------- launch
extern "C" void kernel_launch(void* const* d_in, const int* in_sizes, int n_in,
                              void* d_out, int out_size, void* d_ws, size_t ws_size,
                              hipStream_t stream) {
    const float* X  = (const float*)d_in[0];
    const float* Wq = (const float*)d_in[1];
    const float* Wk = (const float*)d_in[2];
    const float* Wv = (const float*)d_in[3];
    const float* Wo = (const float*)d_in[4];
    const float* bo = (const float*)d_in[5];
    float* out = (float*)d_out;

    char* w = (char*)d_ws;
    unsigned short* Xb   = (unsigned short*)(w);                    // 4 MiB [2048][1024]
    unsigned short* Wb   = (unsigned short*)(w + (4u  << 20));      // 6 MiB [3072][1024]
    unsigned short* Wob  = (unsigned short*)(w + (10u << 20));      // 2 MiB [1024][1024]
    unsigned short* Qb   = (unsigned short*)(w + (12u << 20));      // 12 MiB [3][16][2048][64] bf16
    unsigned short* vhb  = (unsigned short*)(w + (24u << 20));      // 4 MiB [2048][1024] bf16
    float*          nrm  = (float*)(w + (28u << 20));               // 32 f32 (max sumsq per q/k head)
    unsigned short* Ssum = (unsigned short*)(w + (29u << 20));      // 4 MiB [512][64][64] bf16
    float*          zsum = (float*)(w + (34u << 20));               // 128 KiB
    float*          vssum= (float*)(w + (34u << 20) + (1u << 17));  // 128 KiB
    unsigned short* Kb = Qb + 2097152;
    unsigned short* Vb = Qb + 2u * 2097152;

    cast_all<<<6144, 256, 0, stream>>>(X, Wq, Wk, Wv, Wo, Xb, Wb, Wob, nrm);
    gemm_bf16<0, 128, 64, 128><<<dim3(48, 16), 256, 0, stream>>>(Xb, Wb, nullptr, Qb, nullptr, nrm, 2048, 3072, 1024);
    chunk_sums<<<512, 256, 0, stream>>>(Kb, Vb, Ssum, zsum, vssum);
    chunk_scan<<<264, 256, 0, stream>>>(Ssum, zsum, vssum);
    intra_attn<<<512, 256, 0, stream>>>(Qb, Kb, Vb, Ssum, zsum, vssum, nrm, vhb);
    gemm_bf16<1, 64, 128, 128><<<dim3(8, 32), 256, 0, stream>>>(vhb, Wob, out, nullptr, bo, nullptr, 2048, 1024, 1024);
}

// Round 13
// 61.749 us; speedup vs baseline: 1.1174x; 1.0282x over previous
//
#include <hip/hip_runtime.h>

#define N_SEQ 2048
#define NH 16
#define DH 64
#define CHUNK 64
#define NCHUNK 32

typedef float f32x4 __attribute__((ext_vector_type(4)));
typedef __bf16 bf16x8 __attribute__((ext_vector_type(8)));
typedef unsigned short u16x4 __attribute__((ext_vector_type(4)));
typedef unsigned short u16x8 __attribute__((ext_vector_type(8)));

static __device__ inline unsigned short f2b(float x) {
    unsigned int u = __builtin_bit_cast(unsigned int, x);
    unsigned int r = (u + 0x7fffu + ((u >> 16) & 1u)) >> 16;  // RNE
    return (unsigned short)r;
}
static __device__ inline float b2f(unsigned short b) {
    return __builtin_bit_cast(float, (unsigned int)b << 16);
}
// swizzled elem offset in a [rows][64 bf16] LDS tile (row stride 128B)
static __device__ inline int sw(int row, int col) {
    return row * 64 + (col ^ ((row & 7) << 3));
}

// ---------------------------------------------------------------- fused casts (X + 4 weights) + zero norm buffer
__global__ __launch_bounds__(256) void cast_all(
    const float* __restrict__ X, const float* __restrict__ Wq, const float* __restrict__ Wk,
    const float* __restrict__ Wv, const float* __restrict__ Wo,
    unsigned short* __restrict__ Xb, unsigned short* __restrict__ Wb,
    unsigned short* __restrict__ Wob, float* __restrict__ nrm) {
    if (blockIdx.x == 0 && threadIdx.x < 32) nrm[threadIdx.x] = 0.f;
    int i = blockIdx.x * 256 + threadIdx.x;     // float4 id, total 1572864
    const float* src; unsigned short* dst; int off;
    if (i < 524288)       { src = X;  dst = Xb;               off = i; }
    else if (i < 786432)  { src = Wq; dst = Wb;               off = i - 524288; }
    else if (i < 1048576) { src = Wk; dst = Wb + (1u << 20);  off = i - 786432; }
    else if (i < 1310720) { src = Wv; dst = Wb + (2u << 20);  off = i - 1048576; }
    else                  { src = Wo; dst = Wob;              off = i - 1310720; }
    float4 v = reinterpret_cast<const float4*>(src)[off];
    u16x4 o;
    o[0] = f2b(v.x); o[1] = f2b(v.y); o[2] = f2b(v.z); o[3] = f2b(v.w);
    reinterpret_cast<u16x4*>(dst)[off] = o;
}

// ---------------------------------------------------------------- GEMM (bf16 MFMA, BMxBN tile, BK-deep LDS, swizzled)
static __device__ inline void gload_lds16(const unsigned short* g, unsigned short* l) {
    __builtin_amdgcn_global_load_lds(
        (const __attribute__((address_space(1))) unsigned int*)g,
        (__attribute__((address_space(3))) unsigned int*)l, 16, 0, 0);
}

// MODE 0 (BM=128,BN=64): write bf16 QKV [which][h][n][d]; block owns ONE head column-group ->
//   fused per-head max row-sumsq via LDS partials + atomicMax.
// MODE 1 (BM=64,BN=64): f32 out = acc + bias.  (BN=64 -> 512 blocks = 2/CU: the 1-block/CU
//   256-grid was 12.5% occupancy, latency-bound.)
template<int MODE, int BM, int BN, int BK>
__global__ __launch_bounds__(256, 3) void gemm_bf16(
    const unsigned short* __restrict__ A,
    const unsigned short* __restrict__ B,
    float* __restrict__ outf,
    unsigned short* __restrict__ outb,
    const float* __restrict__ bias,
    float* __restrict__ nrm,
    int M, int N, int K)
{
    // LDS: row = BK bf16 (BK/8 16B-slots); logical slot s of row r stored at phys p = s ^ (r&7).
    __shared__ __align__(16) unsigned short As[BM][BK];
    __shared__ __align__(16) unsigned short Bs[BN][BK];
    __shared__ float pnorm[2][BM];

    constexpr int SLOTS = BK / 8;            // 16B-slots per row
    constexpr int RPL   = 64 / SLOTS;        // rows covered per gload (64 lanes x 16B)

    // XCD-aware bijective swizzle (grid count % 8 == 0), bn-major chunks
    const int L = blockIdx.y * gridDim.x + blockIdx.x;
    const int cpx = (gridDim.x * gridDim.y) >> 3;
    const int tile = (L & 7) * cpx + (L >> 3);
    const int bn = tile / gridDim.y;
    const int bm = tile % gridDim.y;

    const int t = threadIdx.x;
    const int wave = t >> 6, lane = t & 63;
    const int wm = wave >> 1, wn = wave & 1;
    const int r16 = lane & 15, ks = lane >> 4;
    constexpr int MFRAG = BM / 32;
    constexpr int NFRAG = BN / 32;

    f32x4 acc[MFRAG][NFRAG] = {};

    const unsigned short* gA = A + (size_t)bm * BM * K;
    const unsigned short* gB = B + (size_t)bn * BN * K;
    const int lrow  = lane / SLOTS;                          // row within gload group
    const int lslot = lane % SLOTS;                          // phys 16B-slot within row
    const int rsw = (r16 & 7);                               // read-side XOR (slot units)

    for (int k0 = 0; k0 < K; k0 += BK) {
        __syncthreads();
        #pragma unroll
        for (int g2 = 0; g2 < BM * SLOTS / 256; ++g2) {
            int r0 = wave * (BM / 4) + g2 * RPL;
            int srccol = ((lslot ^ ((r0 + lrow) & 7)) << 3);   // pre-swizzled source col
            gload_lds16(&gA[(size_t)(r0 + lrow) * K + k0 + srccol], &As[r0][0]);
        }
        #pragma unroll
        for (int g2 = 0; g2 < BN * SLOTS / 256; ++g2) {
            int r0 = wave * (BN / 4) + g2 * RPL;
            int srccol = ((lslot ^ ((r0 + lrow) & 7)) << 3);
            gload_lds16(&gB[(size_t)(r0 + lrow) * K + k0 + srccol], &Bs[r0][0]);
        }
        __syncthreads();

        #pragma unroll
        for (int kk = 0; kk < BK / 32; ++kk) {
            const int sl = ((((kk << 2) + ks) ^ rsw) << 3);   // swizzled elem offset
            bf16x8 af[MFRAG], bfr[NFRAG];
            #pragma unroll
            for (int m = 0; m < MFRAG; ++m)
                af[m] = *reinterpret_cast<const bf16x8*>(&As[wm * (BM / 2) + m * 16 + r16][sl]);
            #pragma unroll
            for (int n = 0; n < NFRAG; ++n)
                bfr[n] = *reinterpret_cast<const bf16x8*>(&Bs[wn * (BN / 2) + n * 16 + r16][sl]);
            #pragma unroll
            for (int m = 0; m < MFRAG; ++m)
                #pragma unroll
                for (int n = 0; n < NFRAG; ++n)
                    acc[m][n] = __builtin_amdgcn_mfma_f32_16x16x32_bf16(af[m], bfr[n], acc[m][n], 0, 0, 0);
        }
    }

    #pragma unroll
    for (int m = 0; m < MFRAG; ++m) {
        int row0 = bm * BM + wm * (BM / 2) + m * 16 + ks * 4;
        #pragma unroll
        for (int n = 0; n < NFRAG; ++n) {
            int col = bn * BN + wn * (BN / 2) + n * 16 + r16;
            if (MODE == 0) {
                int wch = col >> 10, h = (col >> 6) & 15, d = col & 63;
                unsigned short* dst = outb + (size_t)wch * (NH * (size_t)N_SEQ * DH)
                                          + (size_t)h * N_SEQ * DH + d;
                #pragma unroll
                for (int j = 0; j < 4; ++j)
                    dst[(size_t)(row0 + j) * DH] = f2b(acc[m][n][j]);
            } else {
                float bv = bias[col];
                #pragma unroll
                for (int j = 0; j < 4; ++j)
                    outf[(size_t)(row0 + j) * N + col] = acc[m][n][j] + bv;
            }
        }
    }

    // fused per-head max row-sumsq (MODE 0, BN=64: block owns exactly one (which, head))
    if constexpr (MODE == 0) {
        const int wch = bn >> 4;                 // bn in [0,48): 0..15 q, 16..31 k, 32..47 v
        if (wch < 2) {
            const int h = bn & 15;
            #pragma unroll
            for (int m = 0; m < MFRAG; ++m)
                #pragma unroll
                for (int j = 0; j < 4; ++j) {
                    float rs = 0.f;
                    #pragma unroll
                    for (int n = 0; n < NFRAG; ++n) rs = fmaf(acc[m][n][j], acc[m][n][j], rs);
                    rs += __shfl_xor(rs, 1);
                    rs += __shfl_xor(rs, 2);
                    rs += __shfl_xor(rs, 4);
                    rs += __shfl_xor(rs, 8);
                    if (r16 == 0)
                        pnorm[wn][wm * (BM / 2) + m * 16 + ks * 4 + j] = rs;
                }
            __syncthreads();
            if (t < BM) {
                float s = pnorm[0][t] + pnorm[1][t];
                #pragma unroll
                for (int o = 1; o < 64; o <<= 1) s = fmaxf(s, __shfl_xor(s, o));
                if ((t & 63) == 0)
                    atomicMax(reinterpret_cast<unsigned int*>(&nrm[wch * 16 + h]),
                              __builtin_bit_cast(unsigned int, s));
            }
        }
    }
}

// ---------------------------------------------------------------- per-chunk sums via MFMA: S = K^T V (bf16 out), z, vs
__global__ __launch_bounds__(256) void chunk_sums(const unsigned short* __restrict__ Kb,
                                                  const unsigned short* __restrict__ Vb,
                                                  unsigned short* __restrict__ Ssum,
                                                  float* __restrict__ zsum,
                                                  float* __restrict__ vssum) {
    const int h = blockIdx.x >> 5, c = blockIdx.x & 31;
    __shared__ __align__(16) unsigned short Kt[4096];   // [d][j] swizzled (= K^T)
    __shared__ __align__(16) unsigned short Vt[4096];   // [e][j] swizzled (= V^T)
    const size_t off = ((size_t)h * N_SEQ + c * CHUNK) * DH;
    const int t = threadIdx.x, lane = t & 63;

    {   // transposed gather
        const int d = t & 63, j0 = (t >> 6) * 16;
        unsigned short rk[16], rv[16];
        #pragma unroll
        for (int i = 0; i < 16; ++i) {
            rk[i] = Kb[off + (size_t)(j0 + i) * DH + d];
            rv[i] = Vb[off + (size_t)(j0 + i) * DH + d];
        }
        u16x8 a, b;
        #pragma unroll
        for (int i = 0; i < 8; ++i) { a[i] = rk[i]; b[i] = rk[8 + i]; }
        *reinterpret_cast<u16x8*>(&Kt[sw(d, j0)]) = a;
        *reinterpret_cast<u16x8*>(&Kt[sw(d, j0 + 8)]) = b;
        #pragma unroll
        for (int i = 0; i < 8; ++i) { a[i] = rv[i]; b[i] = rv[8 + i]; }
        *reinterpret_cast<u16x8*>(&Vt[sw(d, j0)]) = a;
        *reinterpret_cast<u16x8*>(&Vt[sw(d, j0 + 8)]) = b;
    }
    __syncthreads();

    const int w = t >> 6, cl = lane & 15, g = lane >> 4;
    bf16x8 ak0 = *reinterpret_cast<const bf16x8*>(&Kt[sw(w * 16 + cl, g * 8)]);
    bf16x8 ak1 = *reinterpret_cast<const bf16x8*>(&Kt[sw(w * 16 + cl, 32 + g * 8)]);
    f32x4 acc[4] = {};
    #pragma unroll
    for (int et = 0; et < 4; ++et) {
        bf16x8 b0 = *reinterpret_cast<const bf16x8*>(&Vt[sw(et * 16 + cl, g * 8)]);
        bf16x8 b1 = *reinterpret_cast<const bf16x8*>(&Vt[sw(et * 16 + cl, 32 + g * 8)]);
        acc[et] = __builtin_amdgcn_mfma_f32_16x16x32_bf16(ak0, b0, acc[et], 0, 0, 0);
        acc[et] = __builtin_amdgcn_mfma_f32_16x16x32_bf16(ak1, b1, acc[et], 0, 0, 0);
    }
    unsigned short* So = Ssum + (size_t)blockIdx.x * (DH * DH);
    #pragma unroll
    for (int et = 0; et < 4; ++et)
        #pragma unroll
        for (int j = 0; j < 4; ++j)
            So[(size_t)(w * 16 + g * 4 + j) * DH + et * 16 + cl] = f2b(acc[et][j]);

    if (t < 64) {
        float z = 0.f;
        #pragma unroll
        for (int i = 0; i < 8; ++i) {
            u16x8 v = *reinterpret_cast<const u16x8*>(&Kt[sw(t, i * 8)]);
            #pragma unroll
            for (int k = 0; k < 8; ++k) z += b2f(v[k]);
        }
        zsum[(size_t)blockIdx.x * DH + t] = z;
    } else if (t < 128) {
        int e = t - 64;
        float z = 0.f;
        #pragma unroll
        for (int i = 0; i < 8; ++i) {
            u16x8 v = *reinterpret_cast<const u16x8*>(&Vt[sw(e, i * 8)]);
            #pragma unroll
            for (int k = 0; k < 8; ++k) z += b2f(v[k]);
        }
        vssum[(size_t)blockIdx.x * DH + e] = z;
    }
}

// ---------------------------------------------------------------- exclusive scan over chunks
// register-resident: 32 independent loads (pipelined) -> in-reg scan -> 32 stores.
// (previous load/store/load chain serialized on store-to-load aliasing: 32 dependent L2 RTTs)
__global__ __launch_bounds__(256) void chunk_scan(unsigned short* __restrict__ Ssum,
                                                  float* __restrict__ zsum,
                                                  float* __restrict__ vssum) {
    const int b = blockIdx.x;
    if (b < 256) {
        const int h = b >> 4;
        const int e = (b & 15) * 256 + threadIdx.x;
        size_t base = (size_t)h * NCHUNK * (DH * DH) + e;
        float v[NCHUNK];
        #pragma unroll
        for (int c = 0; c < NCHUNK; ++c) v[c] = b2f(Ssum[base + (size_t)c * (DH * DH)]);
        float run = 0.f;
        #pragma unroll
        for (int c = 0; c < NCHUNK; ++c) { float tmp = v[c]; v[c] = run; run += tmp; }
        #pragma unroll
        for (int c = 0; c < NCHUNK; ++c) Ssum[base + (size_t)c * (DH * DH)] = f2b(v[c]);
    } else {
        const int g = (b - 256) * 256 + threadIdx.x;
        const int which = g >> 10, h = (g >> 6) & 15, e = g & 63;
        float* arr = which ? vssum : zsum;
        size_t base = (size_t)h * NCHUNK * DH + e;
        float v[NCHUNK];
        #pragma unroll
        for (int c = 0; c < NCHUNK; ++c) v[c] = arr[base + (size_t)c * DH];
        float run = 0.f;
        #pragma unroll
        for (int c = 0; c < NCHUNK; ++c) { float tmp = v[c]; v[c] = run; run += tmp; }
        #pragma unroll
        for (int c = 0; c < NCHUNK; ++c) arr[base + (size_t)c * DH] = v[c];
    }
}

// ---------------------------------------------------------------- intra-chunk attention + combine, MFMA
__global__ __launch_bounds__(256) void intra_attn(
    const unsigned short* __restrict__ Qb, const unsigned short* __restrict__ Kb,
    const unsigned short* __restrict__ Vb,
    const unsigned short* __restrict__ Ssum, const float* __restrict__ zsum,
    const float* __restrict__ vssum, const float* __restrict__ nrm,
    unsigned short* __restrict__ vhb) {
    const int h = blockIdx.x >> 5, c = blockIdx.x & 31;
    __shared__ __align__(16) unsigned short Ql[4096];   // [q][d] swizzled
    __shared__ __align__(16) unsigned short Kl[4096];   // [key][d] swizzled
    __shared__ __align__(16) unsigned short Vt[4096];   // [e][key] swizzled
    __shared__ __align__(16) unsigned short Sp[4096];   // [e][d] = bf16(alpha*S_prev[d][e]) swizzled
    __shared__ __align__(16) unsigned short Pl[4096];   // per-wave [16][64] swizzled
    __shared__ float zp[DH], vsp[DH];

    const int t = threadIdx.x, lane = t & 63, w = t >> 6;
    const float alpha = 1.f / sqrtf(nrm[h] * nrm[16 + h]);   // 1/(qn*kn), nrm = max sumsq
    const size_t off = ((size_t)h * N_SEQ + c * CHUNK) * DH;

    // Q, K: row-major coalesced loads, swizzled 16B writes
    #pragma unroll
    for (int p = 0; p < 2; ++p) {
        int lin = t + p * 256;
        int row = lin >> 3, col = (lin & 7) * 8;
        u16x8 q = *reinterpret_cast<const u16x8*>(Qb + off + (size_t)row * DH + col);
        u16x8 k = *reinterpret_cast<const u16x8*>(Kb + off + (size_t)row * DH + col);
        *reinterpret_cast<u16x8*>(&Ql[sw(row, col)]) = q;
        *reinterpret_cast<u16x8*>(&Kl[sw(row, col)]) = k;
    }
    // V transposed gather
    {
        const int e = t & 63, j0 = (t >> 6) * 16;
        unsigned short rv[16];
        #pragma unroll
        for (int i = 0; i < 16; ++i) rv[i] = Vb[off + (size_t)(j0 + i) * DH + e];
        u16x8 a, b;
        #pragma unroll
        for (int i = 0; i < 8; ++i) { a[i] = rv[i]; b[i] = rv[8 + i]; }
        *reinterpret_cast<u16x8*>(&Vt[sw(e, j0)]) = a;
        *reinterpret_cast<u16x8*>(&Vt[sw(e, j0 + 8)]) = b;
    }
    // S_prev transposed gather (bf16 in), alpha-prescaled
    {
        const unsigned short* Sg = Ssum + (size_t)blockIdx.x * (DH * DH);
        const int e = t & 63, d0 = (t >> 6) * 16;
        u16x8 a, b;
        #pragma unroll
        for (int i = 0; i < 8; ++i) a[i] = f2b(alpha * b2f(Sg[(size_t)(d0 + i) * DH + e]));
        #pragma unroll
        for (int i = 0; i < 8; ++i) b[i] = f2b(alpha * b2f(Sg[(size_t)(d0 + 8 + i) * DH + e]));
        *reinterpret_cast<u16x8*>(&Sp[sw(e, d0)]) = a;
        *reinterpret_cast<u16x8*>(&Sp[sw(e, d0 + 8)]) = b;
    }
    if (t < 64) zp[t] = alpha * zsum[(size_t)blockIdx.x * DH + t];
    else if (t < 128) vsp[t - 64] = vssum[(size_t)blockIdx.x * DH + (t - 64)];
    __syncthreads();

    const int cl = lane & 15, g = lane >> 4;
    const int qrow = (w << 4) + cl;

    bf16x8 aq0 = *reinterpret_cast<const bf16x8*>(&Ql[sw(qrow, g * 8)]);
    bf16x8 aq1 = *reinterpret_cast<const bf16x8*>(&Ql[sw(qrow, 32 + g * 8)]);

    // 1) acc = Q @ (alpha*S_prev)
    f32x4 acc[4] = {};
    #pragma unroll
    for (int et = 0; et < 4; ++et) {
        bf16x8 b0 = *reinterpret_cast<const bf16x8*>(&Sp[sw(et * 16 + cl, g * 8)]);
        bf16x8 b1 = *reinterpret_cast<const bf16x8*>(&Sp[sw(et * 16 + cl, 32 + g * 8)]);
        acc[et] = __builtin_amdgcn_mfma_f32_16x16x32_bf16(aq0, b0, acc[et], 0, 0, 0);
        acc[et] = __builtin_amdgcn_mfma_f32_16x16x32_bf16(aq1, b1, acc[et], 0, 0, 0);
    }
    // 2) raw scores S = Q @ K^T
    f32x4 sacc[4] = {};
    #pragma unroll
    for (int kt = 0; kt < 4; ++kt) {
        bf16x8 b0 = *reinterpret_cast<const bf16x8*>(&Kl[sw(kt * 16 + cl, g * 8)]);
        bf16x8 b1 = *reinterpret_cast<const bf16x8*>(&Kl[sw(kt * 16 + cl, 32 + g * 8)]);
        sacc[kt] = __builtin_amdgcn_mfma_f32_16x16x32_bf16(aq0, b0, sacc[kt], 0, 0, 0);
        sacc[kt] = __builtin_amdgcn_mfma_f32_16x16x32_bf16(aq1, b1, sacc[kt], 0, 0, 0);
    }
    // 3) mask + 1 + alpha, den partials, stage P
    unsigned short* Pw = &Pl[w * 1024];
    float part[4] = {0.f, 0.f, 0.f, 0.f};
    #pragma unroll
    for (int kt = 0; kt < 4; ++kt) {
        int key = kt * 16 + cl;
        #pragma unroll
        for (int j = 0; j < 4; ++j) {
            int rr = g * 4 + j;
            int q = (w << 4) + rr;
            float s = (key <= q) ? fmaf(alpha, sacc[kt][j], 1.f) : 0.f;
            part[j] += s;
            Pw[rr * 64 + (key ^ ((rr & 7) << 3))] = f2b(s);
        }
    }
    #pragma unroll
    for (int j = 0; j < 4; ++j) {
        int q = (w << 4) + g * 4 + j;
        float qz = 0.f;
        #pragma unroll
        for (int m = 0; m < 4; ++m) {
            int d = cl + m * 16;
            qz = fmaf(b2f(Ql[sw(q, d)]), zp[d], qz);
        }
        part[j] += qz;
    }
    #pragma unroll
    for (int o = 1; o < 16; o <<= 1)
        #pragma unroll
        for (int j = 0; j < 4; ++j) part[j] += __shfl_xor(part[j], o);
    float invden[4];
    #pragma unroll
    for (int j = 0; j < 4; ++j) invden[j] = 1.f / ((float)(c * CHUNK) + part[j]);

    // 4) acc += P @ V
    #pragma unroll
    for (int ks = 0; ks < 2; ++ks) {
        bf16x8 ap = *reinterpret_cast<const bf16x8*>(&Pw[cl * 64 + ((ks * 32 + g * 8) ^ ((cl & 7) << 3))]);
        #pragma unroll
        for (int et = 0; et < 4; ++et) {
            bf16x8 bv = *reinterpret_cast<const bf16x8*>(&Vt[sw(et * 16 + cl, ks * 32 + g * 8)]);
            acc[et] = __builtin_amdgcn_mfma_f32_16x16x32_bf16(ap, bv, acc[et], 0, 0, 0);
        }
    }
    // 5) epilogue
    #pragma unroll
    for (int et = 0; et < 4; ++et)
        #pragma unroll
        for (int j = 0; j < 4; ++j) {
            int q = (w << 4) + g * 4 + j;
            int e = et * 16 + cl;
            float o = (vsp[e] + acc[et][j]) * invden[j];
            vhb[(size_t)(c * CHUNK + q) * (NH * DH) + h * DH + e] = f2b(o);
        }
}

// ---------------------------------------------------------------- launch
extern "C" void kernel_launch(void* const* d_in, const int* in_sizes, int n_in,
                              void* d_out, int out_size, void* d_ws, size_t ws_size,
                              hipStream_t stream) {
    const float* X  = (const float*)d_in[0];
    const float* Wq = (const float*)d_in[1];
    const float* Wk = (const float*)d_in[2];
    const float* Wv = (const float*)d_in[3];
    const float* Wo = (const float*)d_in[4];
    const float* bo = (const float*)d_in[5];
    float* out = (float*)d_out;

    char* w = (char*)d_ws;
    unsigned short* Xb   = (unsigned short*)(w);                    // 4 MiB [2048][1024]
    unsigned short* Wb   = (unsigned short*)(w + (4u  << 20));      // 6 MiB [3072][1024]
    unsigned short* Wob  = (unsigned short*)(w + (10u << 20));      // 2 MiB [1024][1024]
    unsigned short* Qb   = (unsigned short*)(w + (12u << 20));      // 12 MiB [3][16][2048][64] bf16
    unsigned short* vhb  = (unsigned short*)(w + (24u << 20));      // 4 MiB [2048][1024] bf16
    float*          nrm  = (float*)(w + (28u << 20));               // 32 f32 (max sumsq per q/k head)
    unsigned short* Ssum = (unsigned short*)(w + (29u << 20));      // 4 MiB [512][64][64] bf16
    float*          zsum = (float*)(w + (34u << 20));               // 128 KiB
    float*          vssum= (float*)(w + (34u << 20) + (1u << 17));  // 128 KiB
    unsigned short* Kb = Qb + 2097152;
    unsigned short* Vb = Qb + 2u * 2097152;

    cast_all<<<6144, 256, 0, stream>>>(X, Wq, Wk, Wv, Wo, Xb, Wb, Wob, nrm);
    gemm_bf16<0, 128, 64, 128><<<dim3(48, 16), 256, 0, stream>>>(Xb, Wb, nullptr, Qb, nullptr, nrm, 2048, 3072, 1024);
    chunk_sums<<<512, 256, 0, stream>>>(Kb, Vb, Ssum, zsum, vssum);
    chunk_scan<<<264, 256, 0, stream>>>(Ssum, zsum, vssum);
    intra_attn<<<512, 256, 0, stream>>>(Qb, Kb, Vb, Ssum, zsum, vssum, nrm, vhb);
    gemm_bf16<1, 64, 64, 128><<<dim3(16, 32), 256, 0, stream>>>(vhb, Wob, out, nullptr, bo, nullptr, 2048, 1024, 1024);
}

// Round 14
// 60.629 us; speedup vs baseline: 1.1380x; 1.0185x over previous
//
#include <hip/hip_runtime.h>

#define N_SEQ 2048
#define NH 16
#define DH 64
#define CHUNK 64
#define NCHUNK 32

typedef float f32x4 __attribute__((ext_vector_type(4)));
typedef __bf16 bf16x8 __attribute__((ext_vector_type(8)));
typedef unsigned short u16x4 __attribute__((ext_vector_type(4)));
typedef unsigned short u16x8 __attribute__((ext_vector_type(8)));

static __device__ inline unsigned short f2b(float x) {
    unsigned int u = __builtin_bit_cast(unsigned int, x);
    unsigned int r = (u + 0x7fffu + ((u >> 16) & 1u)) >> 16;  // RNE
    return (unsigned short)r;
}
static __device__ inline float b2f(unsigned short b) {
    return __builtin_bit_cast(float, (unsigned int)b << 16);
}
// swizzled elem offset in a [rows][64 bf16] LDS tile (row stride 128B)
static __device__ inline int sw(int row, int col) {
    return row * 64 + (col ^ ((row & 7) << 3));
}

// ---------------------------------------------------------------- fused casts (X + 4 weights), grid-stride x4
__global__ __launch_bounds__(256) void cast_all(
    const float* __restrict__ X, const float* __restrict__ Wq, const float* __restrict__ Wk,
    const float* __restrict__ Wv, const float* __restrict__ Wo,
    unsigned short* __restrict__ Xb, unsigned short* __restrict__ Wb,
    unsigned short* __restrict__ Wob, float* __restrict__ nrm) {
    if (blockIdx.x == 0 && threadIdx.x < 32) nrm[threadIdx.x] = 0.f;
    #pragma unroll
    for (int it = 0; it < 4; ++it) {
        int i = blockIdx.x * 256 + threadIdx.x + it * 393216;   // float4 id, total 1572864
        const float* src; unsigned short* dst; int off;
        if (i < 524288)       { src = X;  dst = Xb;               off = i; }
        else if (i < 786432)  { src = Wq; dst = Wb;               off = i - 524288; }
        else if (i < 1048576) { src = Wk; dst = Wb + (1u << 20);  off = i - 786432; }
        else if (i < 1310720) { src = Wv; dst = Wb + (2u << 20);  off = i - 1048576; }
        else                  { src = Wo; dst = Wob;              off = i - 1310720; }
        float4 v = reinterpret_cast<const float4*>(src)[off];
        u16x4 o;
        o[0] = f2b(v.x); o[1] = f2b(v.y); o[2] = f2b(v.z); o[3] = f2b(v.w);
        reinterpret_cast<u16x4*>(dst)[off] = o;
    }
}

// ---------------------------------------------------------------- GEMM (bf16 MFMA, BMxBN tile, BK-deep LDS, swizzled)
static __device__ inline void gload_lds16(const unsigned short* g, unsigned short* l) {
    __builtin_amdgcn_global_load_lds(
        (const __attribute__((address_space(1))) unsigned int*)g,
        (__attribute__((address_space(3))) unsigned int*)l, 16, 0, 0);
}

// MODE 0 (BM=128,BN=64,BK=128): write bf16 QKV [which][h][n][d] via LDS-retiled coalesced
//   u16x8 stores (reuses dead As; row pad 80 elems = 160B for even bank spread) + fused
//   per-head max row-sumsq.
// MODE 1 (BM=64,BN=64,BK=256): f32 out = acc + bias; 4 K-steps (half the barrier drains).
template<int MODE, int BM, int BN, int BK>
__global__ __launch_bounds__(256, 3) void gemm_bf16(
    const unsigned short* __restrict__ A,
    const unsigned short* __restrict__ B,
    float* __restrict__ outf,
    unsigned short* __restrict__ outb,
    const float* __restrict__ bias,
    float* __restrict__ nrm,
    int M, int N, int K)
{
    // LDS: row = BK bf16 (BK/8 16B-slots); logical slot s of row r stored at phys p = s ^ (r&7).
    __shared__ __align__(16) unsigned short As[BM][BK];
    __shared__ __align__(16) unsigned short Bs[BN][BK];
    __shared__ float pnorm[2][BM];

    constexpr int SLOTS = BK / 8;            // 16B-slots per row
    constexpr int RPL   = 64 / SLOTS;        // rows covered per gload (64 lanes x 16B)

    // XCD-aware bijective swizzle (grid count % 8 == 0), bn-major chunks
    const int L = blockIdx.y * gridDim.x + blockIdx.x;
    const int cpx = (gridDim.x * gridDim.y) >> 3;
    const int tile = (L & 7) * cpx + (L >> 3);
    const int bn = tile / gridDim.y;
    const int bm = tile % gridDim.y;

    const int t = threadIdx.x;
    const int wave = t >> 6, lane = t & 63;
    const int wm = wave >> 1, wn = wave & 1;
    const int r16 = lane & 15, ks = lane >> 4;
    constexpr int MFRAG = BM / 32;
    constexpr int NFRAG = BN / 32;

    f32x4 acc[MFRAG][NFRAG] = {};

    const unsigned short* gA = A + (size_t)bm * BM * K;
    const unsigned short* gB = B + (size_t)bn * BN * K;
    const int lrow  = lane / SLOTS;                          // row within gload group
    const int lslot = lane % SLOTS;                          // phys 16B-slot within row
    const int rsw = (r16 & 7);                               // read-side XOR (slot units)

    for (int k0 = 0; k0 < K; k0 += BK) {
        __syncthreads();
        #pragma unroll
        for (int g2 = 0; g2 < BM * SLOTS / 256; ++g2) {
            int r0 = wave * (BM / 4) + g2 * RPL;
            int srccol = ((lslot ^ ((r0 + lrow) & 7)) << 3);   // pre-swizzled source col
            gload_lds16(&gA[(size_t)(r0 + lrow) * K + k0 + srccol], &As[r0][0]);
        }
        #pragma unroll
        for (int g2 = 0; g2 < BN * SLOTS / 256; ++g2) {
            int r0 = wave * (BN / 4) + g2 * RPL;
            int srccol = ((lslot ^ ((r0 + lrow) & 7)) << 3);
            gload_lds16(&gB[(size_t)(r0 + lrow) * K + k0 + srccol], &Bs[r0][0]);
        }
        __syncthreads();

        #pragma unroll
        for (int kk = 0; kk < BK / 32; ++kk) {
            const int sl = ((((kk << 2) + ks) ^ rsw) << 3);   // swizzled elem offset
            bf16x8 af[MFRAG], bfr[NFRAG];
            #pragma unroll
            for (int m = 0; m < MFRAG; ++m)
                af[m] = *reinterpret_cast<const bf16x8*>(&As[wm * (BM / 2) + m * 16 + r16][sl]);
            #pragma unroll
            for (int n = 0; n < NFRAG; ++n)
                bfr[n] = *reinterpret_cast<const bf16x8*>(&Bs[wn * (BN / 2) + n * 16 + r16][sl]);
            #pragma unroll
            for (int m = 0; m < MFRAG; ++m)
                #pragma unroll
                for (int n = 0; n < NFRAG; ++n)
                    acc[m][n] = __builtin_amdgcn_mfma_f32_16x16x32_bf16(af[m], bfr[n], acc[m][n], 0, 0, 0);
        }
    }

    if constexpr (MODE == 0) {
        // ---- retiled epilogue: acc -> padded LDS tile (reuse dead As) -> coalesced u16x8 stores
        __syncthreads();                                   // all LDS reads complete
        unsigned short* Ct = &As[0][0];                    // [128][80] padded (20KB <= As)
        #pragma unroll
        for (int m = 0; m < MFRAG; ++m)
            #pragma unroll
            for (int n = 0; n < NFRAG; ++n) {
                int col = wn * (BN / 2) + n * 16 + r16;
                #pragma unroll
                for (int j = 0; j < 4; ++j) {
                    int row = wm * (BM / 2) + m * 16 + ks * 4 + j;
                    Ct[row * 80 + col] = f2b(acc[m][n][j]);
                }
            }
        const int wch = bn >> 4;                 // bn in [0,48): 0..15 q, 16..31 k, 32..47 v
        const int h = bn & 15;
        if (wch < 2) {                           // per-head max row-sumsq partials
            #pragma unroll
            for (int m = 0; m < MFRAG; ++m)
                #pragma unroll
                for (int j = 0; j < 4; ++j) {
                    float rs = 0.f;
                    #pragma unroll
                    for (int n = 0; n < NFRAG; ++n) rs = fmaf(acc[m][n][j], acc[m][n][j], rs);
                    rs += __shfl_xor(rs, 1);
                    rs += __shfl_xor(rs, 2);
                    rs += __shfl_xor(rs, 4);
                    rs += __shfl_xor(rs, 8);
                    if (r16 == 0)
                        pnorm[wn][wm * (BM / 2) + m * 16 + ks * 4 + j] = rs;
                }
        }
        __syncthreads();
        unsigned short* dstb = outb + (size_t)wch * (NH * (size_t)N_SEQ * DH)
                                    + (size_t)h * N_SEQ * DH;
        #pragma unroll
        for (int pass = 0; pass < BM / 32; ++pass) {
            int row = pass * 32 + (t >> 3);
            int dcol = (t & 7) * 8;
            u16x8 vv = *reinterpret_cast<const u16x8*>(&Ct[row * 80 + dcol]);
            *reinterpret_cast<u16x8*>(&dstb[(size_t)(bm * BM + row) * DH + dcol]) = vv;
        }
        if (wch < 2 && t < BM) {
            float s = pnorm[0][t] + pnorm[1][t];
            #pragma unroll
            for (int o = 1; o < 64; o <<= 1) s = fmaxf(s, __shfl_xor(s, o));
            if ((t & 63) == 0)
                atomicMax(reinterpret_cast<unsigned int*>(&nrm[wch * 16 + h]),
                          __builtin_bit_cast(unsigned int, s));
        }
    } else {
        #pragma unroll
        for (int m = 0; m < MFRAG; ++m) {
            int row0 = bm * BM + wm * (BM / 2) + m * 16 + ks * 4;
            #pragma unroll
            for (int n = 0; n < NFRAG; ++n) {
                int col = bn * BN + wn * (BN / 2) + n * 16 + r16;
                float bv = bias[col];
                #pragma unroll
                for (int j = 0; j < 4; ++j)
                    outf[(size_t)(row0 + j) * N + col] = acc[m][n][j] + bv;
            }
        }
    }
}

// ---------------------------------------------------------------- per-chunk sums via MFMA: S = K^T V (bf16 out), z, vs
__global__ __launch_bounds__(256) void chunk_sums(const unsigned short* __restrict__ Kb,
                                                  const unsigned short* __restrict__ Vb,
                                                  unsigned short* __restrict__ Ssum,
                                                  float* __restrict__ zsum,
                                                  float* __restrict__ vssum) {
    const int h = blockIdx.x >> 5, c = blockIdx.x & 31;
    __shared__ __align__(16) unsigned short Kt[4096];   // [d][j] swizzled (= K^T)
    __shared__ __align__(16) unsigned short Vt[4096];   // [e][j] swizzled (= V^T)
    const size_t off = ((size_t)h * N_SEQ + c * CHUNK) * DH;
    const int t = threadIdx.x, lane = t & 63;

    {   // transposed gather
        const int d = t & 63, j0 = (t >> 6) * 16;
        unsigned short rk[16], rv[16];
        #pragma unroll
        for (int i = 0; i < 16; ++i) {
            rk[i] = Kb[off + (size_t)(j0 + i) * DH + d];
            rv[i] = Vb[off + (size_t)(j0 + i) * DH + d];
        }
        u16x8 a, b;
        #pragma unroll
        for (int i = 0; i < 8; ++i) { a[i] = rk[i]; b[i] = rk[8 + i]; }
        *reinterpret_cast<u16x8*>(&Kt[sw(d, j0)]) = a;
        *reinterpret_cast<u16x8*>(&Kt[sw(d, j0 + 8)]) = b;
        #pragma unroll
        for (int i = 0; i < 8; ++i) { a[i] = rv[i]; b[i] = rv[8 + i]; }
        *reinterpret_cast<u16x8*>(&Vt[sw(d, j0)]) = a;
        *reinterpret_cast<u16x8*>(&Vt[sw(d, j0 + 8)]) = b;
    }
    __syncthreads();

    const int w = t >> 6, cl = lane & 15, g = lane >> 4;
    bf16x8 ak0 = *reinterpret_cast<const bf16x8*>(&Kt[sw(w * 16 + cl, g * 8)]);
    bf16x8 ak1 = *reinterpret_cast<const bf16x8*>(&Kt[sw(w * 16 + cl, 32 + g * 8)]);
    f32x4 acc[4] = {};
    #pragma unroll
    for (int et = 0; et < 4; ++et) {
        bf16x8 b0 = *reinterpret_cast<const bf16x8*>(&Vt[sw(et * 16 + cl, g * 8)]);
        bf16x8 b1 = *reinterpret_cast<const bf16x8*>(&Vt[sw(et * 16 + cl, 32 + g * 8)]);
        acc[et] = __builtin_amdgcn_mfma_f32_16x16x32_bf16(ak0, b0, acc[et], 0, 0, 0);
        acc[et] = __builtin_amdgcn_mfma_f32_16x16x32_bf16(ak1, b1, acc[et], 0, 0, 0);
    }
    unsigned short* So = Ssum + (size_t)blockIdx.x * (DH * DH);
    #pragma unroll
    for (int et = 0; et < 4; ++et)
        #pragma unroll
        for (int j = 0; j < 4; ++j)
            So[(size_t)(w * 16 + g * 4 + j) * DH + et * 16 + cl] = f2b(acc[et][j]);

    if (t < 64) {
        float z = 0.f;
        #pragma unroll
        for (int i = 0; i < 8; ++i) {
            u16x8 v = *reinterpret_cast<const u16x8*>(&Kt[sw(t, i * 8)]);
            #pragma unroll
            for (int k = 0; k < 8; ++k) z += b2f(v[k]);
        }
        zsum[(size_t)blockIdx.x * DH + t] = z;
    } else if (t < 128) {
        int e = t - 64;
        float z = 0.f;
        #pragma unroll
        for (int i = 0; i < 8; ++i) {
            u16x8 v = *reinterpret_cast<const u16x8*>(&Vt[sw(e, i * 8)]);
            #pragma unroll
            for (int k = 0; k < 8; ++k) z += b2f(v[k]);
        }
        vssum[(size_t)blockIdx.x * DH + e] = z;
    }
}

// ---------------------------------------------------------------- exclusive scan over chunks (register-resident)
__global__ __launch_bounds__(256) void chunk_scan(unsigned short* __restrict__ Ssum,
                                                  float* __restrict__ zsum,
                                                  float* __restrict__ vssum) {
    const int b = blockIdx.x;
    if (b < 256) {
        const int h = b >> 4;
        const int e = (b & 15) * 256 + threadIdx.x;
        size_t base = (size_t)h * NCHUNK * (DH * DH) + e;
        float v[NCHUNK];
        #pragma unroll
        for (int c = 0; c < NCHUNK; ++c) v[c] = b2f(Ssum[base + (size_t)c * (DH * DH)]);
        float run = 0.f;
        #pragma unroll
        for (int c = 0; c < NCHUNK; ++c) { float tmp = v[c]; v[c] = run; run += tmp; }
        #pragma unroll
        for (int c = 0; c < NCHUNK; ++c) Ssum[base + (size_t)c * (DH * DH)] = f2b(v[c]);
    } else {
        const int g = (b - 256) * 256 + threadIdx.x;
        const int which = g >> 10, h = (g >> 6) & 15, e = g & 63;
        float* arr = which ? vssum : zsum;
        size_t base = (size_t)h * NCHUNK * DH + e;
        float v[NCHUNK];
        #pragma unroll
        for (int c = 0; c < NCHUNK; ++c) v[c] = arr[base + (size_t)c * DH];
        float run = 0.f;
        #pragma unroll
        for (int c = 0; c < NCHUNK; ++c) { float tmp = v[c]; v[c] = run; run += tmp; }
        #pragma unroll
        for (int c = 0; c < NCHUNK; ++c) arr[base + (size_t)c * DH] = v[c];
    }
}

// ---------------------------------------------------------------- intra-chunk attention + combine, MFMA
__global__ __launch_bounds__(256) void intra_attn(
    const unsigned short* __restrict__ Qb, const unsigned short* __restrict__ Kb,
    const unsigned short* __restrict__ Vb,
    const unsigned short* __restrict__ Ssum, const float* __restrict__ zsum,
    const float* __restrict__ vssum, const float* __restrict__ nrm,
    unsigned short* __restrict__ vhb) {
    const int h = blockIdx.x >> 5, c = blockIdx.x & 31;
    __shared__ __align__(16) unsigned short Ql[4096];   // [q][d] swizzled
    __shared__ __align__(16) unsigned short Kl[4096];   // [key][d] swizzled
    __shared__ __align__(16) unsigned short Vt[4096];   // [e][key] swizzled
    __shared__ __align__(16) unsigned short Sp[4096];   // [e][d] = bf16(alpha*S_prev[d][e]) swizzled
    __shared__ __align__(16) unsigned short Pl[4096];   // per-wave [16][64] swizzled
    __shared__ float zp[DH], vsp[DH];

    const int t = threadIdx.x, lane = t & 63, w = t >> 6;
    const float alpha = 1.f / sqrtf(nrm[h] * nrm[16 + h]);   // 1/(qn*kn), nrm = max sumsq
    const size_t off = ((size_t)h * N_SEQ + c * CHUNK) * DH;

    // Q, K: row-major coalesced loads, swizzled 16B writes
    #pragma unroll
    for (int p = 0; p < 2; ++p) {
        int lin = t + p * 256;
        int row = lin >> 3, col = (lin & 7) * 8;
        u16x8 q = *reinterpret_cast<const u16x8*>(Qb + off + (size_t)row * DH + col);
        u16x8 k = *reinterpret_cast<const u16x8*>(Kb + off + (size_t)row * DH + col);
        *reinterpret_cast<u16x8*>(&Ql[sw(row, col)]) = q;
        *reinterpret_cast<u16x8*>(&Kl[sw(row, col)]) = k;
    }
    // V transposed gather
    {
        const int e = t & 63, j0 = (t >> 6) * 16;
        unsigned short rv[16];
        #pragma unroll
        for (int i = 0; i < 16; ++i) rv[i] = Vb[off + (size_t)(j0 + i) * DH + e];
        u16x8 a, b;
        #pragma unroll
        for (int i = 0; i < 8; ++i) { a[i] = rv[i]; b[i] = rv[8 + i]; }
        *reinterpret_cast<u16x8*>(&Vt[sw(e, j0)]) = a;
        *reinterpret_cast<u16x8*>(&Vt[sw(e, j0 + 8)]) = b;
    }
    // S_prev transposed gather (bf16 in), alpha-prescaled
    {
        const unsigned short* Sg = Ssum + (size_t)blockIdx.x * (DH * DH);
        const int e = t & 63, d0 = (t >> 6) * 16;
        u16x8 a, b;
        #pragma unroll
        for (int i = 0; i < 8; ++i) a[i] = f2b(alpha * b2f(Sg[(size_t)(d0 + i) * DH + e]));
        #pragma unroll
        for (int i = 0; i < 8; ++i) b[i] = f2b(alpha * b2f(Sg[(size_t)(d0 + 8 + i) * DH + e]));
        *reinterpret_cast<u16x8*>(&Sp[sw(e, d0)]) = a;
        *reinterpret_cast<u16x8*>(&Sp[sw(e, d0 + 8)]) = b;
    }
    if (t < 64) zp[t] = alpha * zsum[(size_t)blockIdx.x * DH + t];
    else if (t < 128) vsp[t - 64] = vssum[(size_t)blockIdx.x * DH + (t - 64)];
    __syncthreads();

    const int cl = lane & 15, g = lane >> 4;
    const int qrow = (w << 4) + cl;

    bf16x8 aq0 = *reinterpret_cast<const bf16x8*>(&Ql[sw(qrow, g * 8)]);
    bf16x8 aq1 = *reinterpret_cast<const bf16x8*>(&Ql[sw(qrow, 32 + g * 8)]);

    // 1) acc = Q @ (alpha*S_prev)
    f32x4 acc[4] = {};
    #pragma unroll
    for (int et = 0; et < 4; ++et) {
        bf16x8 b0 = *reinterpret_cast<const bf16x8*>(&Sp[sw(et * 16 + cl, g * 8)]);
        bf16x8 b1 = *reinterpret_cast<const bf16x8*>(&Sp[sw(et * 16 + cl, 32 + g * 8)]);
        acc[et] = __builtin_amdgcn_mfma_f32_16x16x32_bf16(aq0, b0, acc[et], 0, 0, 0);
        acc[et] = __builtin_amdgcn_mfma_f32_16x16x32_bf16(aq1, b1, acc[et], 0, 0, 0);
    }
    // 2) raw scores S = Q @ K^T
    f32x4 sacc[4] = {};
    #pragma unroll
    for (int kt = 0; kt < 4; ++kt) {
        bf16x8 b0 = *reinterpret_cast<const bf16x8*>(&Kl[sw(kt * 16 + cl, g * 8)]);
        bf16x8 b1 = *reinterpret_cast<const bf16x8*>(&Kl[sw(kt * 16 + cl, 32 + g * 8)]);
        sacc[kt] = __builtin_amdgcn_mfma_f32_16x16x32_bf16(aq0, b0, sacc[kt], 0, 0, 0);
        sacc[kt] = __builtin_amdgcn_mfma_f32_16x16x32_bf16(aq1, b1, sacc[kt], 0, 0, 0);
    }
    // 3) mask + 1 + alpha, den partials, stage P
    unsigned short* Pw = &Pl[w * 1024];
    float part[4] = {0.f, 0.f, 0.f, 0.f};
    #pragma unroll
    for (int kt = 0; kt < 4; ++kt) {
        int key = kt * 16 + cl;
        #pragma unroll
        for (int j = 0; j < 4; ++j) {
            int rr = g * 4 + j;
            int q = (w << 4) + rr;
            float s = (key <= q) ? fmaf(alpha, sacc[kt][j], 1.f) : 0.f;
            part[j] += s;
            Pw[rr * 64 + (key ^ ((rr & 7) << 3))] = f2b(s);
        }
    }
    #pragma unroll
    for (int j = 0; j < 4; ++j) {
        int q = (w << 4) + g * 4 + j;
        float qz = 0.f;
        #pragma unroll
        for (int m = 0; m < 4; ++m) {
            int d = cl + m * 16;
            qz = fmaf(b2f(Ql[sw(q, d)]), zp[d], qz);
        }
        part[j] += qz;
    }
    #pragma unroll
    for (int o = 1; o < 16; o <<= 1)
        #pragma unroll
        for (int j = 0; j < 4; ++j) part[j] += __shfl_xor(part[j], o);
    float invden[4];
    #pragma unroll
    for (int j = 0; j < 4; ++j) invden[j] = 1.f / ((float)(c * CHUNK) + part[j]);

    // 4) acc += P @ V
    #pragma unroll
    for (int ks = 0; ks < 2; ++ks) {
        bf16x8 ap = *reinterpret_cast<const bf16x8*>(&Pw[cl * 64 + ((ks * 32 + g * 8) ^ ((cl & 7) << 3))]);
        #pragma unroll
        for (int et = 0; et < 4; ++et) {
            bf16x8 bv = *reinterpret_cast<const bf16x8*>(&Vt[sw(et * 16 + cl, ks * 32 + g * 8)]);
            acc[et] = __builtin_amdgcn_mfma_f32_16x16x32_bf16(ap, bv, acc[et], 0, 0, 0);
        }
    }
    // 5) epilogue
    #pragma unroll
    for (int et = 0; et < 4; ++et)
        #pragma unroll
        for (int j = 0; j < 4; ++j) {
            int q = (w << 4) + g * 4 + j;
            int e = et * 16 + cl;
            float o = (vsp[e] + acc[et][j]) * invden[j];
            vhb[(size_t)(c * CHUNK + q) * (NH * DH) + h * DH + e] = f2b(o);
        }
}

// ---------------------------------------------------------------- launch
extern "C" void kernel_launch(void* const* d_in, const int* in_sizes, int n_in,
                              void* d_out, int out_size, void* d_ws, size_t ws_size,
                              hipStream_t stream) {
    const float* X  = (const float*)d_in[0];
    const float* Wq = (const float*)d_in[1];
    const float* Wk = (const float*)d_in[2];
    const float* Wv = (const float*)d_in[3];
    const float* Wo = (const float*)d_in[4];
    const float* bo = (const float*)d_in[5];
    float* out = (float*)d_out;

    char* w = (char*)d_ws;
    unsigned short* Xb   = (unsigned short*)(w);                    // 4 MiB [2048][1024]
    unsigned short* Wb   = (unsigned short*)(w + (4u  << 20));      // 6 MiB [3072][1024]
    unsigned short* Wob  = (unsigned short*)(w + (10u << 20));      // 2 MiB [1024][1024]
    unsigned short* Qb   = (unsigned short*)(w + (12u << 20));      // 12 MiB [3][16][2048][64] bf16
    unsigned short* vhb  = (unsigned short*)(w + (24u << 20));      // 4 MiB [2048][1024] bf16
    float*          nrm  = (float*)(w + (28u << 20));               // 32 f32 (max sumsq per q/k head)
    unsigned short* Ssum = (unsigned short*)(w + (29u << 20));      // 4 MiB [512][64][64] bf16
    float*          zsum = (float*)(w + (34u << 20));               // 128 KiB
    float*          vssum= (float*)(w + (34u << 20) + (1u << 17));  // 128 KiB
    unsigned short* Kb = Qb + 2097152;
    unsigned short* Vb = Qb + 2u * 2097152;

    cast_all<<<1536, 256, 0, stream>>>(X, Wq, Wk, Wv, Wo, Xb, Wb, Wob, nrm);
    gemm_bf16<0, 128, 64, 128><<<dim3(48, 16), 256, 0, stream>>>(Xb, Wb, nullptr, Qb, nullptr, nrm, 2048, 3072, 1024);
    chunk_sums<<<512, 256, 0, stream>>>(Kb, Vb, Ssum, zsum, vssum);
    chunk_scan<<<264, 256, 0, stream>>>(Ssum, zsum, vssum);
    intra_attn<<<512, 256, 0, stream>>>(Qb, Kb, Vb, Ssum, zsum, vssum, nrm, vhb);
    gemm_bf16<1, 64, 64, 256><<<dim3(16, 32), 256, 0, stream>>>(vhb, Wob, out, nullptr, bo, nullptr, 2048, 1024, 1024);
}